// Round 11
// baseline (143.701 us; speedup 1.0000x reference)
//
#include <hip/hip_runtime.h>
#include <math.h>

#define N_SB 2
#define N_V  3
#define N_R  2048
#define N_C  1000
#define N_S  40
#define N_G  15
#define N_HID 256
#define HW 65536
#define CAP 256   // compacted candidate list capacity (expected ~90, max ~125)

__device__ __forceinline__ float wave_sum(float v) {
#pragma unroll
  for (int off = 32; off > 0; off >>= 1) v += __shfl_xor(v, off);
  return v;
}

// XLA/Eigen f32 erf: rational poly in x^2, clamp to +-erfinv(1-2^-23).
// Must stay bit-identical across rounds (pt feeds discrete top-k selection).
__device__ __forceinline__ float erf_xla(float x) {
  const float c = 3.832506856900711f;
  x = fminf(fmaxf(x, -c), c);
  float x2 = __fmul_rn(x, x);
  float p = 0.00022905065861350646f;
  p = __fadd_rn(__fmul_rn(p, x2), 0.0034082910107109506f);
  p = __fadd_rn(__fmul_rn(p, x2), 0.050955695062380861f);
  p = __fadd_rn(__fmul_rn(p, x2), 0.18520832239976145f);
  p = __fadd_rn(__fmul_rn(p, x2), 1.128379143519084f);
  float q = -1.1791602954361697e-7f;
  q = __fadd_rn(__fmul_rn(q, x2), 0.000023547966471313185f);
  q = __fadd_rn(__fmul_rn(q, x2), 0.0010179625278914885f);
  q = __fadd_rn(__fmul_rn(q, x2), 0.014070470171167667f);
  q = __fadd_rn(__fmul_rn(q, x2), 0.11098505178285362f);
  q = __fadd_rn(__fmul_rn(q, x2), 0.49746925110067538f);
  q = __fadd_rn(__fmul_rn(q, x2), 1.0f);
  return __fdiv_rn(__fmul_rn(x, p), q);
}

__device__ __forceinline__ float bitonic64(float v, int lane) {
#pragma unroll
  for (int k = 2; k <= 64; k <<= 1) {
#pragma unroll
    for (int j = k >> 1; j >= 1; j >>= 1) {
      float o = __shfl_xor(v, j);
      bool up = ((lane & k) == 0);
      bool lower = ((lane & j) == 0);
      v = (lower == up) ? fminf(v, o) : fmaxf(v, o);
    }
  }
  return v;
}

// Projection: op-for-op identical to rounds 1-10 (pt must stay bit-exact).
__device__ __forceinline__ void proj_one(
    float zc, float ox, float oy, float oz, float dx, float dy, float dz,
    float R00, float R01, float R02, float t0,
    float R10, float R11, float R12, float t1,
    float R20, float R21, float R22, float t2,
    float fx, float fy, float cx, float cy,
    int& lin_out, float& Zc_out)
{
  const float xw = __fadd_rn(ox, __fmul_rn(zc, dx));
  const float yw = __fadd_rn(oy, __fmul_rn(zc, dy));
  const float zw = __fadd_rn(oz, __fmul_rn(zc, dz));
  const float Xc = __fadd_rn(__fadd_rn(__fadd_rn(__fmul_rn(R00, xw), __fmul_rn(R01, yw)), __fmul_rn(R02, zw)), t0);
  const float Yc = __fadd_rn(__fadd_rn(__fadd_rn(__fmul_rn(R10, xw), __fmul_rn(R11, yw)), __fmul_rn(R12, zw)), t1);
  const float Zc = __fadd_rn(__fadd_rn(__fadd_rn(__fmul_rn(R20, xw), __fmul_rn(R21, yw)), __fmul_rn(R22, zw)), t2);
  const float iu = __fdiv_rn(Xc, Zc);
  const float iv = __fdiv_rn(Yc, Zc);
  const float su = __fadd_rn(__fmul_rn(iu, fx), cx);
  const float sv = __fadd_rn(__fmul_rn(iv, fy), cy);
  const float unorm = __fsub_rn(__fmul_rn(__fmul_rn(su, 1.0f / 256.0f), 2.0f), 1.0f);
  const float vnorm = __fsub_rn(__fmul_rn(__fmul_rn(sv, 1.0f / 256.0f), 2.0f), 1.0f);
  const float xf = __fsub_rn(__fmul_rn(__fmul_rn(__fadd_rn(unorm, 1.0f), 0.5f), 256.0f), 0.5f);
  const float yf = __fsub_rn(__fmul_rn(__fmul_rn(__fadd_rn(vnorm, 1.0f), 0.5f), 256.0f), 0.5f);
  const int px = (int)fminf(fmaxf(rintf(xf), 0.0f), 255.0f);
  const int py = (int)fminf(fmaxf(rintf(yf), 0.0f), 255.0f);
  lin_out = py * 256 + px;
  Zc_out = Zc;
}

// Gate + erf, returns ptv (>=0; 0 when masked). Ops identical to r1-r10.
__device__ __forceinline__ float gate_pv(
    int i, int lin, float Zc, float rd,
    const float* __restrict__ smv, const float* __restrict__ nmv,
    float rdx, float rdy, float rdz, float sshalf)
{
  const float SQRT2 = 1.41421356237309515f;
  float ptv = 0.0f;
  if (i < N_C && fabsf(__fsub_rn(rd, Zc)) < 0.05f) {   // ~3% pass depth-gate
    const float rs = smv[lin];
    const float n0 = nmv[lin];
    const float n1 = nmv[HW + lin];
    const float n2 = nmv[2 * HW + lin];
    const float cosd = __fadd_rn(__fadd_rn(__fmul_rn(rdx, n0), __fmul_rn(rdy, n1)), __fmul_rn(rdz, n2));
    if ((rs != 0.0f) && (cosd <= 0.0f)) {
      const float invv = __fdiv_rn(1.0f, __fmul_rn(rs, SQRT2));
      const float a1 = __fmul_rn(__fsub_rn(__fadd_rn(Zc, sshalf), rd), invv);
      const float a2 = __fmul_rn(__fsub_rn(__fsub_rn(Zc, sshalf), rd), invv);
      ptv = __fmul_rn(0.5f, fabsf(__fsub_rn(erf_xla(a1), erf_xla(a2))));
    }
  }
  return ptv;
}

// r10 structure with the two register-budget pathologies fixed at their roots:
// (1) phase A keeps NOTHING loop-carried in VGPRs: z read from s_zc (stride-1,
//     conflict-free), pt accumulated via rare s_pt fmax-rmw (ptv>0 ~3%).
//     -> kills the 11-dword/thread scratch spill (45 MB WRITE_SIZE).
// (2) F1 m-outer-loop split: 11 weight regs per 64-unit group held across the
//     sample loop (unroll 1 stops re-fusion into the 44-reg arrays the 32-reg
//     budget can't hold) -> kills ~440 L2 weight re-loads/thread (+4.6 MB FETCH).
__global__ __launch_bounds__(256, 8)
void nerf_all(const float* __restrict__ rays, const float* __restrict__ poses,
              const float* __restrict__ focal, const float* __restrict__ cvec,
              const float* __restrict__ dmap, const float* __restrict__ smap,
              const float* __restrict__ nmap, const float* __restrict__ W1,
              const float* __restrict__ b1, const float* __restrict__ W2,
              const float* __restrict__ b2, const float* __restrict__ uc,
              const float* __restrict__ gn, const float* __restrict__ uf,
              float* __restrict__ out)
{
  __shared__ __align__(16) float s_pt[1024];
  __shared__ __align__(16) float s_zc[1024];
  __shared__ float s_lv[CAP];
  __shared__ int   s_li[CAP];
  __shared__ float s_lz[CAP];
  __shared__ int   s_cnt;
  __shared__ float s_cv[100];
  __shared__ int   s_ci[100];
  __shared__ float s_cz[100];
  __shared__ float s_zsel[32];
  __shared__ float s_wtot[4], s_sO[4], s_sZ[4], s_sV[4];
  __shared__ int   s_fl[4];
  __shared__ float s_zarr[N_S], s_darr[N_S];
  __shared__ float s_mlp[N_S * 4];

  const int tid = threadIdx.x;
  const int wid = tid >> 6;
  const int lane = tid & 63;
  const int ray = blockIdx.x;       // one ray per block
  const int sb = ray >> 11;

  // init (ordered vs later use by barrier #1)
  if (tid == 0) s_cnt = 0;
  if (tid < 100) { s_cv[tid] = 0.0f; s_ci[tid] = 0x40000000; s_cz[tid] = 0.0f; }
  if (tid < 32) s_zsel[tid] = 0.0f;

  const float* rp = rays + (size_t)ray * 8;   // uniform per block -> SGPRs
  const float ox = rp[0], oy = rp[1], oz = rp[2];
  const float dx = rp[3], dy = rp[4], dz = rp[5];
  const float nearv = rp[6], farv = rp[7];

  const float lindelta = 0.999f / 999.0f;
  const float ssv = __fdiv_rn(__fsub_rn(farv, nearv), 1000.0f);
  const float sshalf = __fmul_rn(ssv, 0.5f);

  // ---------------- Phase A0: z candidates -> LDS; pt init -------------------
  // Same-thread owns index i throughout phase A: no barrier needed before use.
#pragma unroll
  for (int cch = 0; cch < 4; ++cch) {
    const int i = cch * 256 + tid;
    if (i < N_C) {
      const float u = uc[(size_t)ray * N_C + i];
      const float zs = __fadd_rn(__fmul_rn((float)i, lindelta), __fmul_rn(u, 0.001f));
      s_zc[i] = __fadd_rn(__fmul_rn(nearv, __fsub_rn(1.0f, zs)), __fmul_rn(farv, zs));
    } else {
      s_zc[i] = 0.0f;
    }
    s_pt[i] = 0.0f;
  }

  // ---------------- Phase A: gathers, zero loop-carried VGPR state -----------
#pragma unroll 1
  for (int v = 0; v < N_V; ++v) {
    const float* pp = poses + (size_t)(sb * N_V + v) * 16;
    const float R00 = pp[0], R01 = pp[1], R02 = pp[2], t0 = pp[3];
    const float R10 = pp[4], R11 = pp[5], R12 = pp[6], t1 = pp[7];
    const float R20 = pp[8], R21 = pp[9], R22 = pp[10], t2 = pp[11];
    const float fx = focal[(sb * N_V + v) * 2 + 0];
    const float fy = focal[(sb * N_V + v) * 2 + 1];
    const float cx = cvec[(sb * N_V + v) * 2 + 0];
    const float cy = cvec[(sb * N_V + v) * 2 + 1];
    const float rdx = __fadd_rn(__fadd_rn(__fmul_rn(R00, dx), __fmul_rn(R01, dy)), __fmul_rn(R02, dz));
    const float rdy = __fadd_rn(__fadd_rn(__fmul_rn(R10, dx), __fmul_rn(R11, dy)), __fmul_rn(R12, dz));
    const float rdz = __fadd_rn(__fadd_rn(__fmul_rn(R20, dx), __fmul_rn(R21, dy)), __fmul_rn(R22, dz));
    const float* dmv = dmap + (size_t)(sb * N_V + v) * HW;
    const float* smv = smap + (size_t)(sb * N_V + v) * HW;
    const float* nmv = nmap + (size_t)(sb * N_V + v) * 3 * HW;

    // project 4 chunks (z from LDS), issue all 4 rd loads (pipelined)
    int lin0, lin1, lin2, lin3;
    float Zc0, Zc1, Zc2, Zc3;
    proj_one(s_zc[tid], ox, oy, oz, dx, dy, dz,
             R00, R01, R02, t0, R10, R11, R12, t1, R20, R21, R22, t2,
             fx, fy, cx, cy, lin0, Zc0);
    proj_one(s_zc[256 + tid], ox, oy, oz, dx, dy, dz,
             R00, R01, R02, t0, R10, R11, R12, t1, R20, R21, R22, t2,
             fx, fy, cx, cy, lin1, Zc1);
    proj_one(s_zc[512 + tid], ox, oy, oz, dx, dy, dz,
             R00, R01, R02, t0, R10, R11, R12, t1, R20, R21, R22, t2,
             fx, fy, cx, cy, lin2, Zc2);
    proj_one(s_zc[768 + tid], ox, oy, oz, dx, dy, dz,
             R00, R01, R02, t0, R10, R11, R12, t1, R20, R21, R22, t2,
             fx, fy, cx, cy, lin3, Zc3);
    const float rd0 = dmv[lin0];
    const float rd1 = dmv[lin1];
    const float rd2 = dmv[lin2];
    const float rd3 = dmv[lin3];

    // gate each chunk; accumulate into s_pt (rmw only when ptv>0: fmax with 0
    // is identity since pt>=0 -> exact, and view order v0,v1,v2 is preserved)
    float pv;
    pv = gate_pv(tid, lin0, Zc0, rd0, smv, nmv, rdx, rdy, rdz, sshalf);
    if (pv > 0.0f) s_pt[tid] = fmaxf(s_pt[tid], pv);
    pv = gate_pv(256 + tid, lin1, Zc1, rd1, smv, nmv, rdx, rdy, rdz, sshalf);
    if (pv > 0.0f) s_pt[256 + tid] = fmaxf(s_pt[256 + tid], pv);
    pv = gate_pv(512 + tid, lin2, Zc2, rd2, smv, nmv, rdx, rdy, rdz, sshalf);
    if (pv > 0.0f) s_pt[512 + tid] = fmaxf(s_pt[512 + tid], pv);
    pv = gate_pv(768 + tid, lin3, Zc3, rd3, smv, nmv, rdx, rdy, rdz, sshalf);
    if (pv > 0.0f) s_pt[768 + tid] = fmaxf(s_pt[768 + tid], pv);
  }
  __syncthreads();                                    // #1

  // ---------------- ownership switch: thread owns 4 consecutive samples ------
  const bool act = (tid < 250);
  float ptm[4] = {0.0f, 0.0f, 0.0f, 0.0f};
  float zcr[4] = {0.0f, 0.0f, 0.0f, 0.0f};
  if (act) {
    const float4 p4 = *(const float4*)&s_pt[tid * 4];
    ptm[0] = p4.x; ptm[1] = p4.y; ptm[2] = p4.z; ptm[3] = p4.w;
    const float4 z4 = *(const float4*)&s_zc[tid * 4];
    zcr[0] = z4.x; zcr[1] = z4.y; zcr[2] = z4.z; zcr[3] = z4.w;
  }

  // ---------------- Phase B: block scan + moments ----------------------------
  float lp = 1.0f;
  if (act) {
#pragma unroll
    for (int k = 0; k < 4; ++k) lp = __fmul_rn(lp, __fsub_rn(1.0f, ptm[k]));
  }
  float inc = lp;
#pragma unroll
  for (int off = 1; off < 64; off <<= 1) {
    float o = __shfl_up(inc, off);
    if (lane >= off) inc *= o;
  }
  if (lane == 63) s_wtot[wid] = inc;
  __syncthreads();                                    // #2
  float pw = 1.0f;
  if (wid > 0) pw *= s_wtot[0];
  if (wid > 1) pw *= s_wtot[1];
  if (wid > 2) pw *= s_wtot[2];
  float exc = __shfl_up(inc, 1);
  if (lane == 0) exc = 1.0f;
  exc *= pw;

  float accO = 0.0f, accZO = 0.0f;
  bool anynz = false;
  if (act) {
    float run = exc;
#pragma unroll
    for (int k = 0; k < 4; ++k) {
      float o = ptm[k] * run;
      accO += o;
      accZO += zcr[k] * o;
      anynz |= (o != 0.0f);
      run *= (1.0f - ptm[k]);
    }
  }
  accO = wave_sum(accO);
  accZO = wave_sum(accZO);
  const int anyw = __any(anynz) ? 1 : 0;
  if (lane == 0) { s_sO[wid] = accO; s_sZ[wid] = accZO; s_fl[wid] = anyw; }
  __syncthreads();                                    // #3
  const float tO = s_sO[0] + s_sO[1] + s_sO[2] + s_sO[3];
  const float tZ = s_sZ[0] + s_sZ[1] + s_sZ[2] + s_sZ[3];
  const bool raymask = (s_fl[0] | s_fl[1] | s_fl[2] | s_fl[3]) != 0;
  const float swd = (tO > 0.0f) ? tO : 1.0f;
  const float meanz = __fdiv_rn(tZ, swd);

  float accV = 0.0f;
  if (act) {
    float run = exc;
#pragma unroll
    for (int k = 0; k < 4; ++k) {
      float o = ptm[k] * run;
      float d = zcr[k] - meanz;
      accV += o * d * d;
      run *= (1.0f - ptm[k]);
    }
  }
  accV = wave_sum(accV);
  if (lane == 0) s_sV[wid] = accV;
  __syncthreads();                                    // #4
  const float tV = s_sV[0] + s_sV[1] + s_sV[2] + s_sV[3];
  const float stdz = sqrtf(__fdiv_rn(tV, swd));

  // ---------------- Phase C0: compact nonzero candidates into LDS list -------
  {
    const bool nz0 = act && (ptm[0] > 0.0f);
    const bool nz1 = act && (ptm[1] > 0.0f);
    const bool nz2 = act && (ptm[2] > 0.0f);
    const bool nz3 = act && (ptm[3] > 0.0f);
    const int nloc = (int)nz0 + (int)nz1 + (int)nz2 + (int)nz3;
    int base = 0;
    if (nloc > 0) base = atomicAdd(&s_cnt, nloc);
    if (base + nloc <= CAP) {
      int off = base;
      if (nz0) { s_lv[off] = ptm[0]; s_li[off] = tid * 4 + 0; s_lz[off] = zcr[0]; ++off; }
      if (nz1) { s_lv[off] = ptm[1]; s_li[off] = tid * 4 + 1; s_lz[off] = zcr[1]; ++off; }
      if (nz2) { s_lv[off] = ptm[2]; s_li[off] = tid * 4 + 2; s_lz[off] = zcr[2]; ++off; }
      if (nz3) { s_lv[off] = ptm[3]; s_li[off] = tid * 4 + 3; s_lz[off] = zcr[3]; ++off; }
    }
  }
  __syncthreads();                                    // #5
  const int cnt = s_cnt;   // block-uniform

  if (cnt <= CAP) {
    // -------------- Phase C-fast: wave-0 top-25 over compacted list ----------
    if (wid == 0) {
      float rv[4]; int ri[4]; float rz[4];
#pragma unroll
      for (int j = 0; j < 4; ++j) {
        const int p = lane + j * 64;
        if (p < cnt) { rv[j] = s_lv[p]; ri[j] = s_li[p]; rz[j] = s_lz[p]; }
        else         { rv[j] = -2.0f; ri[j] = 0x40000000; rz[j] = 0.0f; }
      }
#pragma unroll 1
      for (int kk = 0; kk < 25; ++kk) {
        float bv = -2.0f; int bi = 0x40000000;
#pragma unroll
        for (int j = 0; j < 4; ++j) {
          if (rv[j] > bv || (rv[j] == bv && ri[j] < bi)) { bv = rv[j]; bi = ri[j]; }
        }
#pragma unroll
        for (int off = 1; off < 64; off <<= 1) {
          const float ov = __shfl_xor(bv, off);
          const int oi = __shfl_xor(bi, off);
          if (ov > bv || (ov == bv && oi < bi)) { bv = ov; bi = oi; }
        }
        if (bv <= 0.0f) break;   // rest of zsel stay 0 (== reference)
#pragma unroll
        for (int j = 0; j < 4; ++j) {
          if (ri[j] == bi) {      // unique global idx: exactly one lane fires
            s_zsel[kk] = rz[j];   // same-wave LDS RAW: in-order
            rv[j] = -1.0f;
          }
        }
      }
    }
  } else {
    // -------------- Phase C-fallback (exact, any data) -----------------------
    const int cbase = wid * 25;
#pragma unroll 1
    for (int kk = 0; kk < 25; ++kk) {
      float bv = -2.0f;
      int bi = 0x40000000;
      if (act) {
#pragma unroll
        for (int k = 0; k < 4; ++k) {
          if (ptm[k] > bv) { bv = ptm[k]; bi = tid * 4 + k; }
        }
      }
#pragma unroll
      for (int off = 1; off < 64; off <<= 1) {
        float ov = __shfl_xor(bv, off);
        int oi = __shfl_xor(bi, off);
        if (ov > bv || (ov == bv && oi < bi)) { bv = ov; bi = oi; }
      }
      if (bv <= 0.0f) break;
      if (tid == (bi >> 2)) {
        s_cv[cbase + kk] = bv;
        s_ci[cbase + kk] = bi;
        const int r = bi & 3;
        float zk;
        if (r == 0)      { zk = zcr[0]; ptm[0] = -1.0f; }
        else if (r == 1) { zk = zcr[1]; ptm[1] = -1.0f; }
        else if (r == 2) { zk = zcr[2]; ptm[2] = -1.0f; }
        else             { zk = zcr[3]; ptm[3] = -1.0f; }
        s_cz[cbase + kk] = zk;
      }
    }
    __syncthreads();
    if (wid == 0) {
      float c0v = s_cv[lane];
      int   c0i = s_ci[lane];
      float c0z = s_cz[lane];
      float c1v = -2.0f; int c1i = 0x40000000; float c1z = 0.0f;
      if (lane + 64 < 100) { c1v = s_cv[lane + 64]; c1i = s_ci[lane + 64]; c1z = s_cz[lane + 64]; }
#pragma unroll 1
      for (int kk = 0; kk < 25; ++kk) {
        float bv = c0v; int bi = c0i; float bz = c0z;
        if (c1v > bv || (c1v == bv && c1i < bi)) { bv = c1v; bi = c1i; bz = c1z; }
#pragma unroll
        for (int off = 1; off < 64; off <<= 1) {
          float ov = __shfl_xor(bv, off);
          int oi = __shfl_xor(bi, off);
          float oz = __shfl_xor(bz, off);
          if (ov > bv || (ov == bv && oi < bi)) { bv = ov; bi = oi; bz = oz; }
        }
        if (bv <= 0.0f) break;
        if (lane == 0) s_zsel[kk] = bz;
        if (c0i == bi) c0v = -1.0f;
        if (c1i == bi) c1v = -1.0f;
      }
    }
  }

  // zero F1 partial buffer using waves 1-3 (wave 0 is busy with D/E below);
  // ordered before F1's += by barrier #6
  if (tid >= 64 && tid < 64 + N_S * 4) s_mlp[tid - 64] = 0.0f;

  // ---------------- Phase D/E: gaussian slots, sort, fill, sort (wave 0) -----
  if (wid == 0) {
    float sortv;
    if (lane < N_S - N_G) {
      sortv = s_zsel[lane];
    } else if (lane < N_S) {
      const float g = gn[(size_t)ray * N_G + (lane - (N_S - N_G))];
      sortv = raymask ? (g * stdz + meanz) : 0.0f;
    } else {
      sortv = INFINITY;
    }
    float z = bitonic64(sortv, lane);
    const bool miss = (lane < N_S) && (z == 0.0f);
    const int nmiss_raw = __popcll(__ballot(miss));
    const int nmiss = (nmiss_raw < 1) ? 1 : nmiss_raw;
    const float stepf = __fdiv_rn(__fsub_rn(farv, nearv), (float)nmiss);
    if (miss) {
      const float ufv = uf[(size_t)ray * N_S + lane];
      z = __fadd_rn(__fadd_rn(nearv, __fmul_rn((float)lane, stepf)), __fmul_rn(ufv, stepf));
    }
    z = bitonic64(z, lane);
    const float zn = __shfl_down(z, 1);
    const float delta = (lane == N_S - 1) ? (farv - z) : (zn - z);
    if (lane < N_S) { s_zarr[lane] = z; s_darr[lane] = delta; }
  }
  __syncthreads();                                    // #6

  // ---------------- Phase F1: MLP, m-outer split (11 weight regs held) -------
  // Each m-pass handles 64 hidden units; partials accumulate in s_mlp (same
  // wave owns its samples across m -> in-order LDS rmw, no barrier needed).
  {
#pragma unroll 1
    for (int m = 0; m < 4; ++m) {
      const int j = lane + 64 * m;
      const float w10 = W1[0 * N_HID + j];
      const float w11 = W1[1 * N_HID + j];
      const float w12 = W1[2 * N_HID + j];
      const float w13 = W1[3 * N_HID + j];
      const float w14 = W1[4 * N_HID + j];
      const float w15 = W1[5 * N_HID + j];
      const float b1j = b1[j];
      const float4 w2j = *(const float4*)(W2 + (size_t)j * 4);
#pragma unroll 1
      for (int q = 0; q < 10; ++q) {
        const int s = wid * 10 + q;
        const float zq = s_zarr[s];
        const float px = ox + zq * dx;
        const float py = oy + zq * dy;
        const float pz = oz + zq * dz;
        float h = b1j;
        h = fmaf(px, w10, h);
        h = fmaf(py, w11, h);
        h = fmaf(pz, w12, h);
        h = fmaf(dx, w13, h);
        h = fmaf(dy, w14, h);
        h = fmaf(dz, w15, h);
        h = fmaxf(h, 0.0f);
        float a0 = h * w2j.x, a1 = h * w2j.y, a2 = h * w2j.z, a3 = h * w2j.w;
        // 4-channel butterfly: lane (l&3) ends with channel (l&3) wave-total
        const float s0 = __shfl_xor(a0, 1), s1 = __shfl_xor(a1, 1);
        const float s2 = __shfl_xor(a2, 1), s3 = __shfl_xor(a3, 1);
        const float m0 = (lane & 1) ? (a1 + s1) : (a0 + s0);
        const float m1 = (lane & 1) ? (a3 + s3) : (a2 + s2);
        const float t0 = __shfl_xor(m0, 2), t1 = __shfl_xor(m1, 2);
        float r = (lane & 2) ? (m1 + t1) : (m0 + t0);
#pragma unroll
        for (int off = 4; off < 64; off <<= 1) r += __shfl_xor(r, off);
        if (lane < 4) s_mlp[s * 4 + lane] += r;
      }
    }
  }
  __syncthreads();                                    // #7

  // ---------------- Phase F2: composite + output (wave 0) --------------------
  if (wid == 0) {
    float alpha = 0.0f, r0 = 0.0f, r1 = 0.0f, r2 = 0.0f, zl = 0.0f;
    float factor = 1.0f;
    if (lane < N_S) {
      zl = s_zarr[lane];
      const float dl = s_darr[lane];
      r0 = s_mlp[lane * 4 + 0] + b2[0];
      r1 = s_mlp[lane * 4 + 1] + b2[1];
      r2 = s_mlp[lane * 4 + 2] + b2[2];
      const float rsig = fmaxf(s_mlp[lane * 4 + 3] + b2[3], 0.0f);
      alpha = 1.0f - expf(-dl * rsig);
      factor = (1.0f - alpha) + 1e-10f;
    }
    float incp = factor;
#pragma unroll
    for (int off = 1; off < 64; off <<= 1) {
      float o = __shfl_up(incp, off);
      if (lane >= off) incp *= o;
    }
    float T = __shfl_up(incp, 1);
    if (lane == 0) T = 1.0f;

    const float w = (lane < N_S) ? alpha * T : 0.0f;
    const float wz = (lane < N_S) ? w * zl : 0.0f;
    const float wr0 = (lane < N_S) ? w * r0 : 0.0f;
    const float wr1 = (lane < N_S) ? w * r1 : 0.0f;
    const float wr2 = (lane < N_S) ? w * r2 : 0.0f;

    const float wsum = wave_sum(w);
    const float dsum = wave_sum(wz);
    const float c0s = wave_sum(wr0);
    const float c1s = wave_sum(wr1);
    const float c2s = wave_sum(wr2);

    if (lane < N_S) out[(size_t)ray * N_S + lane] = w;
    if (lane == 0) {
      float* rgbo = out + (size_t)N_SB * N_R * N_S + (size_t)ray * 3;
      rgbo[0] = (c0s + 1.0f) - wsum;
      rgbo[1] = (c1s + 1.0f) - wsum;
      rgbo[2] = (c2s + 1.0f) - wsum;
      out[(size_t)N_SB * N_R * N_S + (size_t)N_SB * N_R * 3 + ray] = dsum;
    }
  }
}

extern "C" void kernel_launch(void* const* d_in, const int* in_sizes, int n_in,
                              void* d_out, int out_size, void* d_ws, size_t ws_size,
                              hipStream_t stream) {
  const float* rays  = (const float*)d_in[0];
  const float* poses = (const float*)d_in[1];
  const float* focal = (const float*)d_in[2];
  const float* cvec  = (const float*)d_in[3];
  const float* dmap  = (const float*)d_in[4];
  const float* smap  = (const float*)d_in[5];
  const float* nmap  = (const float*)d_in[6];
  const float* W1p   = (const float*)d_in[7];
  const float* b1p   = (const float*)d_in[8];
  const float* W2p   = (const float*)d_in[9];
  const float* b2p   = (const float*)d_in[10];
  const float* ucp   = (const float*)d_in[11];
  const float* gnp   = (const float*)d_in[12];
  const float* ufp   = (const float*)d_in[13];
  float* outp = (float*)d_out;

  dim3 grid(N_SB * N_R);   // one ray per block
  dim3 block(256);
  nerf_all<<<grid, block, 0, stream>>>(rays, poses, focal, cvec, dmap, smap, nmap,
                                       W1p, b1p, W2p, b2p, ucp, gnp, ufp, outp);
}

// Round 12
// 93.116 us; speedup vs baseline: 1.5433x; 1.5433x over previous
//
#include <hip/hip_runtime.h>
#include <math.h>

#define N_SB 2
#define N_V  3
#define N_R  2048
#define N_C  1000
#define N_S  40
#define N_G  15
#define N_HID 256
#define HW 65536
#define CAP 256   // compacted candidate list capacity (expected ~90, max ~125)

__device__ __forceinline__ float wave_sum(float v) {
#pragma unroll
  for (int off = 32; off > 0; off >>= 1) v += __shfl_xor(v, off);
  return v;
}

// XLA/Eigen f32 erf: rational poly in x^2, clamp to +-erfinv(1-2^-23).
// Must stay bit-identical across rounds (pt feeds discrete top-k selection).
__device__ __forceinline__ float erf_xla(float x) {
  const float c = 3.832506856900711f;
  x = fminf(fmaxf(x, -c), c);
  float x2 = __fmul_rn(x, x);
  float p = 0.00022905065861350646f;
  p = __fadd_rn(__fmul_rn(p, x2), 0.0034082910107109506f);
  p = __fadd_rn(__fmul_rn(p, x2), 0.050955695062380861f);
  p = __fadd_rn(__fmul_rn(p, x2), 0.18520832239976145f);
  p = __fadd_rn(__fmul_rn(p, x2), 1.128379143519084f);
  float q = -1.1791602954361697e-7f;
  q = __fadd_rn(__fmul_rn(q, x2), 0.000023547966471313185f);
  q = __fadd_rn(__fmul_rn(q, x2), 0.0010179625278914885f);
  q = __fadd_rn(__fmul_rn(q, x2), 0.014070470171167667f);
  q = __fadd_rn(__fmul_rn(q, x2), 0.11098505178285362f);
  q = __fadd_rn(__fmul_rn(q, x2), 0.49746925110067538f);
  q = __fadd_rn(__fmul_rn(q, x2), 1.0f);
  return __fdiv_rn(__fmul_rn(x, p), q);
}

__device__ __forceinline__ float bitonic64(float v, int lane) {
#pragma unroll
  for (int k = 2; k <= 64; k <<= 1) {
#pragma unroll
    for (int j = k >> 1; j >= 1; j >>= 1) {
      float o = __shfl_xor(v, j);
      bool up = ((lane & k) == 0);
      bool lower = ((lane & j) == 0);
      v = (lower == up) ? fminf(v, o) : fmaxf(v, o);
    }
  }
  return v;
}

// Projection: op-for-op identical to rounds 1-11 (pt must stay bit-exact).
__device__ __forceinline__ void proj_one(
    float zc, float ox, float oy, float oz, float dx, float dy, float dz,
    float R00, float R01, float R02, float t0,
    float R10, float R11, float R12, float t1,
    float R20, float R21, float R22, float t2,
    float fx, float fy, float cx, float cy,
    int& lin_out, float& Zc_out)
{
  const float xw = __fadd_rn(ox, __fmul_rn(zc, dx));
  const float yw = __fadd_rn(oy, __fmul_rn(zc, dy));
  const float zw = __fadd_rn(oz, __fmul_rn(zc, dz));
  const float Xc = __fadd_rn(__fadd_rn(__fadd_rn(__fmul_rn(R00, xw), __fmul_rn(R01, yw)), __fmul_rn(R02, zw)), t0);
  const float Yc = __fadd_rn(__fadd_rn(__fadd_rn(__fmul_rn(R10, xw), __fmul_rn(R11, yw)), __fmul_rn(R12, zw)), t1);
  const float Zc = __fadd_rn(__fadd_rn(__fadd_rn(__fmul_rn(R20, xw), __fmul_rn(R21, yw)), __fmul_rn(R22, zw)), t2);
  const float iu = __fdiv_rn(Xc, Zc);
  const float iv = __fdiv_rn(Yc, Zc);
  const float su = __fadd_rn(__fmul_rn(iu, fx), cx);
  const float sv = __fadd_rn(__fmul_rn(iv, fy), cy);
  const float unorm = __fsub_rn(__fmul_rn(__fmul_rn(su, 1.0f / 256.0f), 2.0f), 1.0f);
  const float vnorm = __fsub_rn(__fmul_rn(__fmul_rn(sv, 1.0f / 256.0f), 2.0f), 1.0f);
  const float xf = __fsub_rn(__fmul_rn(__fmul_rn(__fadd_rn(unorm, 1.0f), 0.5f), 256.0f), 0.5f);
  const float yf = __fsub_rn(__fmul_rn(__fmul_rn(__fadd_rn(vnorm, 1.0f), 0.5f), 256.0f), 0.5f);
  const int px = (int)fminf(fmaxf(rintf(xf), 0.0f), 255.0f);
  const int py = (int)fminf(fmaxf(rintf(yf), 0.0f), 255.0f);
  lin_out = py * 256 + px;
  Zc_out = Zc;
}

// Gate + erf, fmax-accumulate. Ops identical to r1-r11.
__device__ __forceinline__ float gate_one(
    int i, int lin, float Zc, float rd,
    const float* __restrict__ smv, const float* __restrict__ nmv,
    float rdx, float rdy, float rdz, float sshalf, float cur)
{
  const float SQRT2 = 1.41421356237309515f;
  if (i < N_C && fabsf(__fsub_rn(rd, Zc)) < 0.05f) {   // ~3% pass depth-gate
    const float rs = smv[lin];
    const float n0 = nmv[lin];
    const float n1 = nmv[HW + lin];
    const float n2 = nmv[2 * HW + lin];
    const float cosd = __fadd_rn(__fadd_rn(__fmul_rn(rdx, n0), __fmul_rn(rdy, n1)), __fmul_rn(rdz, n2));
    if ((rs != 0.0f) && (cosd <= 0.0f)) {
      const float invv = __fdiv_rn(1.0f, __fmul_rn(rs, SQRT2));
      const float a1 = __fmul_rn(__fsub_rn(__fadd_rn(Zc, sshalf), rd), invv);
      const float a2 = __fmul_rn(__fsub_rn(__fsub_rn(Zc, sshalf), rd), invv);
      const float ptv = __fmul_rn(0.5f, fabsf(__fsub_rn(erf_xla(a1), erf_xla(a2))));
      cur = fmaxf(cur, ptv);
    }
  }
  return cur;
}

// r9/r10 champion structure (~97us). New: views in THIS DATASET share
// bit-identical pose/focal/c -> uv/lin/Zc identical across views (fp ops on
// identical input bits give identical output bits). Runtime bitwise check
// (block-uniform scalar predicate); fast path projects ONCE and gathers all
// 3 views' maps at the same lin (projection VALU + divides 3x down). Exact
// generic fallback for non-uniform data. Spill at (256,8) stays: r6-r11
// proved 45 MB write-once scratch is cheaper than any spill-free variant.
__global__ __launch_bounds__(256, 8)
void nerf_all(const float* __restrict__ rays, const float* __restrict__ poses,
              const float* __restrict__ focal, const float* __restrict__ cvec,
              const float* __restrict__ dmap, const float* __restrict__ smap,
              const float* __restrict__ nmap, const float* __restrict__ W1,
              const float* __restrict__ b1, const float* __restrict__ W2,
              const float* __restrict__ b2, const float* __restrict__ uc,
              const float* __restrict__ gn, const float* __restrict__ uf,
              float* __restrict__ out)
{
  __shared__ __align__(16) float s_pt[1024];
  __shared__ __align__(16) float s_zc[1024];
  __shared__ float s_lv[CAP];
  __shared__ int   s_li[CAP];
  __shared__ float s_lz[CAP];
  __shared__ int   s_cnt;
  __shared__ float s_cv[100];
  __shared__ int   s_ci[100];
  __shared__ float s_cz[100];
  __shared__ float s_zsel[32];
  __shared__ float s_wtot[4], s_sO[4], s_sZ[4], s_sV[4];
  __shared__ int   s_fl[4];
  __shared__ float s_zarr[N_S], s_darr[N_S];
  __shared__ float s_mlp[N_S * 4];

  const int tid = threadIdx.x;
  const int wid = tid >> 6;
  const int lane = tid & 63;
  const int ray = blockIdx.x;       // one ray per block
  const int sb = ray >> 11;

  // init (ordered vs later use by barrier #1)
  if (tid == 0) s_cnt = 0;
  if (tid < 100) { s_cv[tid] = 0.0f; s_ci[tid] = 0x40000000; s_cz[tid] = 0.0f; }
  if (tid < 32) s_zsel[tid] = 0.0f;

  const float* rp = rays + (size_t)ray * 8;   // uniform per block -> SGPRs
  const float ox = rp[0], oy = rp[1], oz = rp[2];
  const float dx = rp[3], dy = rp[4], dz = rp[5];
  const float nearv = rp[6], farv = rp[7];

  const float lindelta = 0.999f / 999.0f;
  const float ssv = __fdiv_rn(__fsub_rn(farv, nearv), 1000.0f);
  const float sshalf = __fmul_rn(ssv, 0.5f);

  // ---------------- Phase A0: z candidates (registers + LDS copy) ------------
  float zg0 = 0.0f, zg1 = 0.0f, zg2 = 0.0f, zg3 = 0.0f;
  {
    const float u0 = uc[(size_t)ray * N_C + tid];
    const float u1 = uc[(size_t)ray * N_C + 256 + tid];
    const float u2 = uc[(size_t)ray * N_C + 512 + tid];
    float zs;
    zs = __fadd_rn(__fmul_rn((float)tid, lindelta), __fmul_rn(u0, 0.001f));
    zg0 = __fadd_rn(__fmul_rn(nearv, __fsub_rn(1.0f, zs)), __fmul_rn(farv, zs));
    s_zc[tid] = zg0;
    zs = __fadd_rn(__fmul_rn((float)(256 + tid), lindelta), __fmul_rn(u1, 0.001f));
    zg1 = __fadd_rn(__fmul_rn(nearv, __fsub_rn(1.0f, zs)), __fmul_rn(farv, zs));
    s_zc[256 + tid] = zg1;
    zs = __fadd_rn(__fmul_rn((float)(512 + tid), lindelta), __fmul_rn(u2, 0.001f));
    zg2 = __fadd_rn(__fmul_rn(nearv, __fsub_rn(1.0f, zs)), __fmul_rn(farv, zs));
    s_zc[512 + tid] = zg2;
    if (768 + tid < N_C) {
      const float u3 = uc[(size_t)ray * N_C + 768 + tid];
      zs = __fadd_rn(__fmul_rn((float)(768 + tid), lindelta), __fmul_rn(u3, 0.001f));
      zg3 = __fadd_rn(__fmul_rn(nearv, __fsub_rn(1.0f, zs)), __fmul_rn(farv, zs));
      s_zc[768 + tid] = zg3;
    }
  }

  // ---------------- view-uniformity check (bitwise, block-uniform) -----------
  bool uni = true;
  {
    const float* p0 = poses + (size_t)(sb * N_V + 0) * 16;
    const float* p1 = poses + (size_t)(sb * N_V + 1) * 16;
    const float* p2 = poses + (size_t)(sb * N_V + 2) * 16;
#pragma unroll
    for (int i = 0; i < 12; ++i) {   // rows 0..2 of the 3x4 [R|t] are all that's used
      uni = uni && (__float_as_uint(p0[i]) == __float_as_uint(p1[i]));
      uni = uni && (__float_as_uint(p0[i]) == __float_as_uint(p2[i]));
    }
#pragma unroll
    for (int i = 0; i < 2; ++i) {
      uni = uni && (__float_as_uint(focal[(sb * N_V + 0) * 2 + i]) == __float_as_uint(focal[(sb * N_V + 1) * 2 + i]));
      uni = uni && (__float_as_uint(focal[(sb * N_V + 0) * 2 + i]) == __float_as_uint(focal[(sb * N_V + 2) * 2 + i]));
      uni = uni && (__float_as_uint(cvec[(sb * N_V + 0) * 2 + i]) == __float_as_uint(cvec[(sb * N_V + 1) * 2 + i]));
      uni = uni && (__float_as_uint(cvec[(sb * N_V + 0) * 2 + i]) == __float_as_uint(cvec[(sb * N_V + 2) * 2 + i]));
    }
  }

  // ---------------- Phase A ---------------------------------------------------
  float ptg0 = 0.0f, ptg1 = 0.0f, ptg2 = 0.0f, ptg3 = 0.0f;
  if (uni) {
    // ---- fast path: project once (v0 constants), gather all 3 views --------
    const float* pp = poses + (size_t)(sb * N_V) * 16;
    const float R00 = pp[0], R01 = pp[1], R02 = pp[2], t0 = pp[3];
    const float R10 = pp[4], R11 = pp[5], R12 = pp[6], t1 = pp[7];
    const float R20 = pp[8], R21 = pp[9], R22 = pp[10], t2 = pp[11];
    const float fx = focal[(sb * N_V) * 2 + 0];
    const float fy = focal[(sb * N_V) * 2 + 1];
    const float cx = cvec[(sb * N_V) * 2 + 0];
    const float cy = cvec[(sb * N_V) * 2 + 1];
    const float rdx = __fadd_rn(__fadd_rn(__fmul_rn(R00, dx), __fmul_rn(R01, dy)), __fmul_rn(R02, dz));
    const float rdy = __fadd_rn(__fadd_rn(__fmul_rn(R10, dx), __fmul_rn(R11, dy)), __fmul_rn(R12, dz));
    const float rdz = __fadd_rn(__fadd_rn(__fmul_rn(R20, dx), __fmul_rn(R21, dy)), __fmul_rn(R22, dz));
    const float* dm0 = dmap + (size_t)(sb * N_V + 0) * HW;
    const float* dm1 = dmap + (size_t)(sb * N_V + 1) * HW;
    const float* dm2 = dmap + (size_t)(sb * N_V + 2) * HW;
    const float* sm0 = smap + (size_t)(sb * N_V + 0) * HW;
    const float* sm1 = smap + (size_t)(sb * N_V + 1) * HW;
    const float* sm2 = smap + (size_t)(sb * N_V + 2) * HW;
    const float* nm0 = nmap + (size_t)(sb * N_V + 0) * 3 * HW;
    const float* nm1 = nmap + (size_t)(sb * N_V + 1) * 3 * HW;
    const float* nm2 = nmap + (size_t)(sb * N_V + 2) * 3 * HW;

    int lin0, lin1, lin2, lin3;
    float Zc0, Zc1, Zc2, Zc3;
    proj_one(zg0, ox, oy, oz, dx, dy, dz,
             R00, R01, R02, t0, R10, R11, R12, t1, R20, R21, R22, t2,
             fx, fy, cx, cy, lin0, Zc0);
    proj_one(zg1, ox, oy, oz, dx, dy, dz,
             R00, R01, R02, t0, R10, R11, R12, t1, R20, R21, R22, t2,
             fx, fy, cx, cy, lin1, Zc1);
    proj_one(zg2, ox, oy, oz, dx, dy, dz,
             R00, R01, R02, t0, R10, R11, R12, t1, R20, R21, R22, t2,
             fx, fy, cx, cy, lin2, Zc2);
    proj_one(zg3, ox, oy, oz, dx, dy, dz,
             R00, R01, R02, t0, R10, R11, R12, t1, R20, R21, R22, t2,
             fx, fy, cx, cy, lin3, Zc3);

    // 12 gathers issued together (deep MLP); same lin per chunk across views
    const float rd00 = dm0[lin0], rd01 = dm1[lin0], rd02 = dm2[lin0];
    const float rd10 = dm0[lin1], rd11 = dm1[lin1], rd12 = dm2[lin1];
    const float rd20 = dm0[lin2], rd21 = dm1[lin2], rd22 = dm2[lin2];
    const float rd30 = dm0[lin3], rd31 = dm1[lin3], rd32 = dm2[lin3];

    // fmax over views: values >=0 finite -> any order exact; keep v0,v1,v2
    ptg0 = gate_one(tid, lin0, Zc0, rd00, sm0, nm0, rdx, rdy, rdz, sshalf, ptg0);
    ptg0 = gate_one(tid, lin0, Zc0, rd01, sm1, nm1, rdx, rdy, rdz, sshalf, ptg0);
    ptg0 = gate_one(tid, lin0, Zc0, rd02, sm2, nm2, rdx, rdy, rdz, sshalf, ptg0);
    ptg1 = gate_one(256 + tid, lin1, Zc1, rd10, sm0, nm0, rdx, rdy, rdz, sshalf, ptg1);
    ptg1 = gate_one(256 + tid, lin1, Zc1, rd11, sm1, nm1, rdx, rdy, rdz, sshalf, ptg1);
    ptg1 = gate_one(256 + tid, lin1, Zc1, rd12, sm2, nm2, rdx, rdy, rdz, sshalf, ptg1);
    ptg2 = gate_one(512 + tid, lin2, Zc2, rd20, sm0, nm0, rdx, rdy, rdz, sshalf, ptg2);
    ptg2 = gate_one(512 + tid, lin2, Zc2, rd21, sm1, nm1, rdx, rdy, rdz, sshalf, ptg2);
    ptg2 = gate_one(512 + tid, lin2, Zc2, rd22, sm2, nm2, rdx, rdy, rdz, sshalf, ptg2);
    ptg3 = gate_one(768 + tid, lin3, Zc3, rd30, sm0, nm0, rdx, rdy, rdz, sshalf, ptg3);
    ptg3 = gate_one(768 + tid, lin3, Zc3, rd31, sm1, nm1, rdx, rdy, rdz, sshalf, ptg3);
    ptg3 = gate_one(768 + tid, lin3, Zc3, rd32, sm2, nm2, rdx, rdy, rdz, sshalf, ptg3);
  } else {
    // ---- generic fallback: per-view projection (r9 loop, exact) ------------
#pragma unroll 1
    for (int v = 0; v < N_V; ++v) {
      const float* pp = poses + (size_t)(sb * N_V + v) * 16;
      const float R00 = pp[0], R01 = pp[1], R02 = pp[2], t0 = pp[3];
      const float R10 = pp[4], R11 = pp[5], R12 = pp[6], t1 = pp[7];
      const float R20 = pp[8], R21 = pp[9], R22 = pp[10], t2 = pp[11];
      const float fx = focal[(sb * N_V + v) * 2 + 0];
      const float fy = focal[(sb * N_V + v) * 2 + 1];
      const float cx = cvec[(sb * N_V + v) * 2 + 0];
      const float cy = cvec[(sb * N_V + v) * 2 + 1];
      const float rdx = __fadd_rn(__fadd_rn(__fmul_rn(R00, dx), __fmul_rn(R01, dy)), __fmul_rn(R02, dz));
      const float rdy = __fadd_rn(__fadd_rn(__fmul_rn(R10, dx), __fmul_rn(R11, dy)), __fmul_rn(R12, dz));
      const float rdz = __fadd_rn(__fadd_rn(__fmul_rn(R20, dx), __fmul_rn(R21, dy)), __fmul_rn(R22, dz));
      const float* dmv = dmap + (size_t)(sb * N_V + v) * HW;
      const float* smv = smap + (size_t)(sb * N_V + v) * HW;
      const float* nmv = nmap + (size_t)(sb * N_V + v) * 3 * HW;

      int lin0, lin1, lin2, lin3;
      float Zc0, Zc1, Zc2, Zc3;
      proj_one(zg0, ox, oy, oz, dx, dy, dz,
               R00, R01, R02, t0, R10, R11, R12, t1, R20, R21, R22, t2,
               fx, fy, cx, cy, lin0, Zc0);
      proj_one(zg1, ox, oy, oz, dx, dy, dz,
               R00, R01, R02, t0, R10, R11, R12, t1, R20, R21, R22, t2,
               fx, fy, cx, cy, lin1, Zc1);
      proj_one(zg2, ox, oy, oz, dx, dy, dz,
               R00, R01, R02, t0, R10, R11, R12, t1, R20, R21, R22, t2,
               fx, fy, cx, cy, lin2, Zc2);
      proj_one(zg3, ox, oy, oz, dx, dy, dz,
               R00, R01, R02, t0, R10, R11, R12, t1, R20, R21, R22, t2,
               fx, fy, cx, cy, lin3, Zc3);
      const float rd0 = dmv[lin0];
      const float rd1 = dmv[lin1];
      const float rd2 = dmv[lin2];
      const float rd3 = dmv[lin3];
      ptg0 = gate_one(tid,       lin0, Zc0, rd0, smv, nmv, rdx, rdy, rdz, sshalf, ptg0);
      ptg1 = gate_one(256 + tid, lin1, Zc1, rd1, smv, nmv, rdx, rdy, rdz, sshalf, ptg1);
      ptg2 = gate_one(512 + tid, lin2, Zc2, rd2, smv, nmv, rdx, rdy, rdz, sshalf, ptg2);
      ptg3 = gate_one(768 + tid, lin3, Zc3, rd3, smv, nmv, rdx, rdy, rdz, sshalf, ptg3);
    }
  }
  s_pt[tid] = ptg0;
  s_pt[256 + tid] = ptg1;
  s_pt[512 + tid] = ptg2;
  if (768 + tid < N_C) s_pt[768 + tid] = ptg3;
  __syncthreads();                                    // #1

  // ---------------- ownership switch: thread owns 4 consecutive samples ------
  const bool act = (tid < 250);
  float ptm[4] = {0.0f, 0.0f, 0.0f, 0.0f};
  float zcr[4] = {0.0f, 0.0f, 0.0f, 0.0f};
  if (act) {
    const float4 p4 = *(const float4*)&s_pt[tid * 4];
    ptm[0] = p4.x; ptm[1] = p4.y; ptm[2] = p4.z; ptm[3] = p4.w;
    const float4 z4 = *(const float4*)&s_zc[tid * 4];
    zcr[0] = z4.x; zcr[1] = z4.y; zcr[2] = z4.z; zcr[3] = z4.w;
  }

  // ---------------- Phase B: block scan + moments ----------------------------
  float lp = 1.0f;
  if (act) {
#pragma unroll
    for (int k = 0; k < 4; ++k) lp = __fmul_rn(lp, __fsub_rn(1.0f, ptm[k]));
  }
  float inc = lp;
#pragma unroll
  for (int off = 1; off < 64; off <<= 1) {
    float o = __shfl_up(inc, off);
    if (lane >= off) inc *= o;
  }
  if (lane == 63) s_wtot[wid] = inc;
  __syncthreads();                                    // #2
  float pw = 1.0f;
  if (wid > 0) pw *= s_wtot[0];
  if (wid > 1) pw *= s_wtot[1];
  if (wid > 2) pw *= s_wtot[2];
  float exc = __shfl_up(inc, 1);
  if (lane == 0) exc = 1.0f;
  exc *= pw;

  float accO = 0.0f, accZO = 0.0f;
  bool anynz = false;
  if (act) {
    float run = exc;
#pragma unroll
    for (int k = 0; k < 4; ++k) {
      float o = ptm[k] * run;
      accO += o;
      accZO += zcr[k] * o;
      anynz |= (o != 0.0f);
      run *= (1.0f - ptm[k]);
    }
  }
  accO = wave_sum(accO);
  accZO = wave_sum(accZO);
  const int anyw = __any(anynz) ? 1 : 0;
  if (lane == 0) { s_sO[wid] = accO; s_sZ[wid] = accZO; s_fl[wid] = anyw; }
  __syncthreads();                                    // #3
  const float tO = s_sO[0] + s_sO[1] + s_sO[2] + s_sO[3];
  const float tZ = s_sZ[0] + s_sZ[1] + s_sZ[2] + s_sZ[3];
  const bool raymask = (s_fl[0] | s_fl[1] | s_fl[2] | s_fl[3]) != 0;
  const float swd = (tO > 0.0f) ? tO : 1.0f;
  const float meanz = __fdiv_rn(tZ, swd);

  float accV = 0.0f;
  if (act) {
    float run = exc;
#pragma unroll
    for (int k = 0; k < 4; ++k) {
      float o = ptm[k] * run;
      float d = zcr[k] - meanz;
      accV += o * d * d;
      run *= (1.0f - ptm[k]);
    }
  }
  accV = wave_sum(accV);
  if (lane == 0) s_sV[wid] = accV;
  __syncthreads();                                    // #4
  const float tV = s_sV[0] + s_sV[1] + s_sV[2] + s_sV[3];
  const float stdz = sqrtf(__fdiv_rn(tV, swd));

  // ---------------- Phase C0: compact nonzero candidates into LDS list -------
  {
    const bool nz0 = act && (ptm[0] > 0.0f);
    const bool nz1 = act && (ptm[1] > 0.0f);
    const bool nz2 = act && (ptm[2] > 0.0f);
    const bool nz3 = act && (ptm[3] > 0.0f);
    const int nloc = (int)nz0 + (int)nz1 + (int)nz2 + (int)nz3;
    int base = 0;
    if (nloc > 0) base = atomicAdd(&s_cnt, nloc);
    if (base + nloc <= CAP) {
      int off = base;
      if (nz0) { s_lv[off] = ptm[0]; s_li[off] = tid * 4 + 0; s_lz[off] = zcr[0]; ++off; }
      if (nz1) { s_lv[off] = ptm[1]; s_li[off] = tid * 4 + 1; s_lz[off] = zcr[1]; ++off; }
      if (nz2) { s_lv[off] = ptm[2]; s_li[off] = tid * 4 + 2; s_lz[off] = zcr[2]; ++off; }
      if (nz3) { s_lv[off] = ptm[3]; s_li[off] = tid * 4 + 3; s_lz[off] = zcr[3]; ++off; }
    }
  }
  __syncthreads();                                    // #5
  const int cnt = s_cnt;   // block-uniform

  if (cnt <= CAP) {
    // -------------- Phase C-fast: wave-0 top-25 over compacted list ----------
    if (wid == 0) {
      float rv[4]; int ri[4]; float rz[4];
#pragma unroll
      for (int j = 0; j < 4; ++j) {
        const int p = lane + j * 64;
        if (p < cnt) { rv[j] = s_lv[p]; ri[j] = s_li[p]; rz[j] = s_lz[p]; }
        else         { rv[j] = -2.0f; ri[j] = 0x40000000; rz[j] = 0.0f; }
      }
#pragma unroll 1
      for (int kk = 0; kk < 25; ++kk) {
        float bv = -2.0f; int bi = 0x40000000;
#pragma unroll
        for (int j = 0; j < 4; ++j) {
          if (rv[j] > bv || (rv[j] == bv && ri[j] < bi)) { bv = rv[j]; bi = ri[j]; }
        }
#pragma unroll
        for (int off = 1; off < 64; off <<= 1) {
          const float ov = __shfl_xor(bv, off);
          const int oi = __shfl_xor(bi, off);
          if (ov > bv || (ov == bv && oi < bi)) { bv = ov; bi = oi; }
        }
        if (bv <= 0.0f) break;   // rest of zsel stay 0 (== reference)
#pragma unroll
        for (int j = 0; j < 4; ++j) {
          if (ri[j] == bi) {      // unique global idx: exactly one lane fires
            s_zsel[kk] = rz[j];   // same-wave LDS RAW: in-order
            rv[j] = -1.0f;
          }
        }
      }
    }
  } else {
    // -------------- Phase C-fallback (exact, any data) -----------------------
    const int cbase = wid * 25;
#pragma unroll 1
    for (int kk = 0; kk < 25; ++kk) {
      float bv = -2.0f;
      int bi = 0x40000000;
      if (act) {
#pragma unroll
        for (int k = 0; k < 4; ++k) {
          if (ptm[k] > bv) { bv = ptm[k]; bi = tid * 4 + k; }
        }
      }
#pragma unroll
      for (int off = 1; off < 64; off <<= 1) {
        float ov = __shfl_xor(bv, off);
        int oi = __shfl_xor(bi, off);
        if (ov > bv || (ov == bv && oi < bi)) { bv = ov; bi = oi; }
      }
      if (bv <= 0.0f) break;
      if (tid == (bi >> 2)) {
        s_cv[cbase + kk] = bv;
        s_ci[cbase + kk] = bi;
        const int r = bi & 3;
        float zk;
        if (r == 0)      { zk = zcr[0]; ptm[0] = -1.0f; }
        else if (r == 1) { zk = zcr[1]; ptm[1] = -1.0f; }
        else if (r == 2) { zk = zcr[2]; ptm[2] = -1.0f; }
        else             { zk = zcr[3]; ptm[3] = -1.0f; }
        s_cz[cbase + kk] = zk;
      }
    }
    __syncthreads();
    if (wid == 0) {
      float c0v = s_cv[lane];
      int   c0i = s_ci[lane];
      float c0z = s_cz[lane];
      float c1v = -2.0f; int c1i = 0x40000000; float c1z = 0.0f;
      if (lane + 64 < 100) { c1v = s_cv[lane + 64]; c1i = s_ci[lane + 64]; c1z = s_cz[lane + 64]; }
#pragma unroll 1
      for (int kk = 0; kk < 25; ++kk) {
        float bv = c0v; int bi = c0i; float bz = c0z;
        if (c1v > bv || (c1v == bv && c1i < bi)) { bv = c1v; bi = c1i; bz = c1z; }
#pragma unroll
        for (int off = 1; off < 64; off <<= 1) {
          float ov = __shfl_xor(bv, off);
          int oi = __shfl_xor(bi, off);
          float oz = __shfl_xor(bz, off);
          if (ov > bv || (ov == bv && oi < bi)) { bv = ov; bi = oi; bz = oz; }
        }
        if (bv <= 0.0f) break;
        if (lane == 0) s_zsel[kk] = bz;
        if (c0i == bi) c0v = -1.0f;
        if (c1i == bi) c1v = -1.0f;
      }
    }
  }

  // ---------------- Phase D/E: gaussian slots, sort, fill, sort (wave 0) -----
  if (wid == 0) {
    float sortv;
    if (lane < N_S - N_G) {
      sortv = s_zsel[lane];
    } else if (lane < N_S) {
      const float g = gn[(size_t)ray * N_G + (lane - (N_S - N_G))];
      sortv = raymask ? (g * stdz + meanz) : 0.0f;
    } else {
      sortv = INFINITY;
    }
    float z = bitonic64(sortv, lane);
    const bool miss = (lane < N_S) && (z == 0.0f);
    const int nmiss_raw = __popcll(__ballot(miss));
    const int nmiss = (nmiss_raw < 1) ? 1 : nmiss_raw;
    const float stepf = __fdiv_rn(__fsub_rn(farv, nearv), (float)nmiss);
    if (miss) {
      const float ufv = uf[(size_t)ray * N_S + lane];
      z = __fadd_rn(__fadd_rn(nearv, __fmul_rn((float)lane, stepf)), __fmul_rn(ufv, stepf));
    }
    z = bitonic64(z, lane);
    const float zn = __shfl_down(z, 1);
    const float delta = (lane == N_S - 1) ? (farv - z) : (zn - z);
    if (lane < N_S) { s_zarr[lane] = z; s_darr[lane] = delta; }
  }
  __syncthreads();                                    // #6

  // ---------------- Phase F1: MLP, 10 samples/wave, multi-channel reduce -----
  {
    const float b2r = (lane < 4) ? b2[lane] : 0.0f;
    float w1r[24], b1r[4], w2r[16];
#pragma unroll
    for (int m = 0; m < 4; ++m) {
      const int j = lane + 64 * m;
#pragma unroll
      for (int k = 0; k < 6; ++k) w1r[k * 4 + m] = W1[k * N_HID + j];
      b1r[m] = b1[j];
      const float4 w2v = *(const float4*)(W2 + (size_t)j * 4);
      w2r[m * 4 + 0] = w2v.x; w2r[m * 4 + 1] = w2v.y;
      w2r[m * 4 + 2] = w2v.z; w2r[m * 4 + 3] = w2v.w;
    }
#pragma unroll 1
    for (int q = 0; q < 10; ++q) {
      const int s = wid * 10 + q;
      const float zq = s_zarr[s];
      const float px = ox + zq * dx;
      const float py = oy + zq * dy;
      const float pz = oz + zq * dz;
      float a0 = 0.0f, a1 = 0.0f, a2 = 0.0f, a3 = 0.0f;
#pragma unroll
      for (int m = 0; m < 4; ++m) {
        float h = b1r[m];
        h = fmaf(px, w1r[0 * 4 + m], h);
        h = fmaf(py, w1r[1 * 4 + m], h);
        h = fmaf(pz, w1r[2 * 4 + m], h);
        h = fmaf(dx, w1r[3 * 4 + m], h);
        h = fmaf(dy, w1r[4 * 4 + m], h);
        h = fmaf(dz, w1r[5 * 4 + m], h);
        h = fmaxf(h, 0.0f);
        a0 = fmaf(h, w2r[m * 4 + 0], a0);
        a1 = fmaf(h, w2r[m * 4 + 1], a1);
        a2 = fmaf(h, w2r[m * 4 + 2], a2);
        a3 = fmaf(h, w2r[m * 4 + 3], a3);
      }
      // multi-channel butterfly: lane (l&3) ends with channel (l&3) total
      const float s0 = __shfl_xor(a0, 1), s1 = __shfl_xor(a1, 1);
      const float s2 = __shfl_xor(a2, 1), s3 = __shfl_xor(a3, 1);
      const float m0 = (lane & 1) ? (a1 + s1) : (a0 + s0);
      const float m1 = (lane & 1) ? (a3 + s3) : (a2 + s2);
      const float t0 = __shfl_xor(m0, 2), t1 = __shfl_xor(m1, 2);
      float r = (lane & 2) ? (m1 + t1) : (m0 + t0);
#pragma unroll
      for (int off = 4; off < 64; off <<= 1) r += __shfl_xor(r, off);
      if (lane < 4) s_mlp[s * 4 + lane] = r + b2r;
    }
  }
  __syncthreads();                                    // #7

  // ---------------- Phase F2: composite + output (wave 0) --------------------
  if (wid == 0) {
    float alpha = 0.0f, r0 = 0.0f, r1 = 0.0f, r2 = 0.0f, zl = 0.0f;
    float factor = 1.0f;
    if (lane < N_S) {
      zl = s_zarr[lane];
      const float dl = s_darr[lane];
      r0 = s_mlp[lane * 4 + 0];
      r1 = s_mlp[lane * 4 + 1];
      r2 = s_mlp[lane * 4 + 2];
      const float rsig = fmaxf(s_mlp[lane * 4 + 3], 0.0f);
      alpha = 1.0f - expf(-dl * rsig);
      factor = (1.0f - alpha) + 1e-10f;
    }
    float incp = factor;
#pragma unroll
    for (int off = 1; off < 64; off <<= 1) {
      float o = __shfl_up(incp, off);
      if (lane >= off) incp *= o;
    }
    float T = __shfl_up(incp, 1);
    if (lane == 0) T = 1.0f;

    const float w = (lane < N_S) ? alpha * T : 0.0f;
    const float wz = (lane < N_S) ? w * zl : 0.0f;
    const float wr0 = (lane < N_S) ? w * r0 : 0.0f;
    const float wr1 = (lane < N_S) ? w * r1 : 0.0f;
    const float wr2 = (lane < N_S) ? w * r2 : 0.0f;

    const float wsum = wave_sum(w);
    const float dsum = wave_sum(wz);
    const float c0s = wave_sum(wr0);
    const float c1s = wave_sum(wr1);
    const float c2s = wave_sum(wr2);

    if (lane < N_S) out[(size_t)ray * N_S + lane] = w;
    if (lane == 0) {
      float* rgbo = out + (size_t)N_SB * N_R * N_S + (size_t)ray * 3;
      rgbo[0] = (c0s + 1.0f) - wsum;
      rgbo[1] = (c1s + 1.0f) - wsum;
      rgbo[2] = (c2s + 1.0f) - wsum;
      out[(size_t)N_SB * N_R * N_S + (size_t)N_SB * N_R * 3 + ray] = dsum;
    }
  }
}

extern "C" void kernel_launch(void* const* d_in, const int* in_sizes, int n_in,
                              void* d_out, int out_size, void* d_ws, size_t ws_size,
                              hipStream_t stream) {
  const float* rays  = (const float*)d_in[0];
  const float* poses = (const float*)d_in[1];
  const float* focal = (const float*)d_in[2];
  const float* cvec  = (const float*)d_in[3];
  const float* dmap  = (const float*)d_in[4];
  const float* smap  = (const float*)d_in[5];
  const float* nmap  = (const float*)d_in[6];
  const float* W1p   = (const float*)d_in[7];
  const float* b1p   = (const float*)d_in[8];
  const float* W2p   = (const float*)d_in[9];
  const float* b2p   = (const float*)d_in[10];
  const float* ucp   = (const float*)d_in[11];
  const float* gnp   = (const float*)d_in[12];
  const float* ufp   = (const float*)d_in[13];
  float* outp = (float*)d_out;

  dim3 grid(N_SB * N_R);   // one ray per block
  dim3 block(256);
  nerf_all<<<grid, block, 0, stream>>>(rays, poses, focal, cvec, dmap, smap, nmap,
                                       W1p, b1p, W2p, b2p, ucp, gnp, ufp, outp);
}

// Round 13
// 93.099 us; speedup vs baseline: 1.5435x; 1.0002x over previous
//
#include <hip/hip_runtime.h>
#include <math.h>

#define N_SB 2
#define N_V  3
#define N_R  2048
#define N_C  1000
#define N_S  40
#define N_G  15
#define N_HID 256
#define HW 65536
#define CAP 256   // compacted candidate list capacity (expected ~90, max ~125)

__device__ __forceinline__ float wave_sum(float v) {
#pragma unroll
  for (int off = 32; off > 0; off >>= 1) v += __shfl_xor(v, off);
  return v;
}

// XLA/Eigen f32 erf: rational poly in x^2, clamp to +-erfinv(1-2^-23).
// Must stay bit-identical across rounds (pt feeds discrete top-k selection).
__device__ __forceinline__ float erf_xla(float x) {
  const float c = 3.832506856900711f;
  x = fminf(fmaxf(x, -c), c);
  float x2 = __fmul_rn(x, x);
  float p = 0.00022905065861350646f;
  p = __fadd_rn(__fmul_rn(p, x2), 0.0034082910107109506f);
  p = __fadd_rn(__fmul_rn(p, x2), 0.050955695062380861f);
  p = __fadd_rn(__fmul_rn(p, x2), 0.18520832239976145f);
  p = __fadd_rn(__fmul_rn(p, x2), 1.128379143519084f);
  float q = -1.1791602954361697e-7f;
  q = __fadd_rn(__fmul_rn(q, x2), 0.000023547966471313185f);
  q = __fadd_rn(__fmul_rn(q, x2), 0.0010179625278914885f);
  q = __fadd_rn(__fmul_rn(q, x2), 0.014070470171167667f);
  q = __fadd_rn(__fmul_rn(q, x2), 0.11098505178285362f);
  q = __fadd_rn(__fmul_rn(q, x2), 0.49746925110067538f);
  q = __fadd_rn(__fmul_rn(q, x2), 1.0f);
  return __fdiv_rn(__fmul_rn(x, p), q);
}

__device__ __forceinline__ float bitonic64(float v, int lane) {
#pragma unroll
  for (int k = 2; k <= 64; k <<= 1) {
#pragma unroll
    for (int j = k >> 1; j >= 1; j >>= 1) {
      float o = __shfl_xor(v, j);
      bool up = ((lane & k) == 0);
      bool lower = ((lane & j) == 0);
      v = (lower == up) ? fminf(v, o) : fmaxf(v, o);
    }
  }
  return v;
}

// Projection: op-for-op identical to rounds 1-12 (pt must stay bit-exact).
__device__ __forceinline__ void proj_one(
    float zc, float ox, float oy, float oz, float dx, float dy, float dz,
    float R00, float R01, float R02, float t0,
    float R10, float R11, float R12, float t1,
    float R20, float R21, float R22, float t2,
    float fx, float fy, float cx, float cy,
    int& lin_out, float& Zc_out)
{
  const float xw = __fadd_rn(ox, __fmul_rn(zc, dx));
  const float yw = __fadd_rn(oy, __fmul_rn(zc, dy));
  const float zw = __fadd_rn(oz, __fmul_rn(zc, dz));
  const float Xc = __fadd_rn(__fadd_rn(__fadd_rn(__fmul_rn(R00, xw), __fmul_rn(R01, yw)), __fmul_rn(R02, zw)), t0);
  const float Yc = __fadd_rn(__fadd_rn(__fadd_rn(__fmul_rn(R10, xw), __fmul_rn(R11, yw)), __fmul_rn(R12, zw)), t1);
  const float Zc = __fadd_rn(__fadd_rn(__fadd_rn(__fmul_rn(R20, xw), __fmul_rn(R21, yw)), __fmul_rn(R22, zw)), t2);
  const float iu = __fdiv_rn(Xc, Zc);
  const float iv = __fdiv_rn(Yc, Zc);
  const float su = __fadd_rn(__fmul_rn(iu, fx), cx);
  const float sv = __fadd_rn(__fmul_rn(iv, fy), cy);
  const float unorm = __fsub_rn(__fmul_rn(__fmul_rn(su, 1.0f / 256.0f), 2.0f), 1.0f);
  const float vnorm = __fsub_rn(__fmul_rn(__fmul_rn(sv, 1.0f / 256.0f), 2.0f), 1.0f);
  const float xf = __fsub_rn(__fmul_rn(__fmul_rn(__fadd_rn(unorm, 1.0f), 0.5f), 256.0f), 0.5f);
  const float yf = __fsub_rn(__fmul_rn(__fmul_rn(__fadd_rn(vnorm, 1.0f), 0.5f), 256.0f), 0.5f);
  const int px = (int)fminf(fmaxf(rintf(xf), 0.0f), 255.0f);
  const int py = (int)fminf(fmaxf(rintf(yf), 0.0f), 255.0f);
  lin_out = py * 256 + px;
  Zc_out = Zc;
}

// Gate + erf, fmax-accumulate. Ops identical to r1-r12.
__device__ __forceinline__ float gate_one(
    int i, int lin, float Zc, float rd,
    const float* __restrict__ smv, const float* __restrict__ nmv,
    float rdx, float rdy, float rdz, float sshalf, float cur)
{
  const float SQRT2 = 1.41421356237309515f;
  if (i < N_C && fabsf(__fsub_rn(rd, Zc)) < 0.05f) {   // ~3% pass depth-gate
    const float rs = smv[lin];
    const float n0 = nmv[lin];
    const float n1 = nmv[HW + lin];
    const float n2 = nmv[2 * HW + lin];
    const float cosd = __fadd_rn(__fadd_rn(__fmul_rn(rdx, n0), __fmul_rn(rdy, n1)), __fmul_rn(rdz, n2));
    if ((rs != 0.0f) && (cosd <= 0.0f)) {
      const float invv = __fdiv_rn(1.0f, __fmul_rn(rs, SQRT2));
      const float a1 = __fmul_rn(__fsub_rn(__fadd_rn(Zc, sshalf), rd), invv);
      const float a2 = __fmul_rn(__fsub_rn(__fsub_rn(Zc, sshalf), rd), invv);
      const float ptv = __fmul_rn(0.5f, fabsf(__fsub_rn(erf_xla(a1), erf_xla(a2))));
      cur = fmaxf(cur, ptv);
    }
  }
  return cur;
}

// r12 champion (93us) + ONE change: sb-partitioned XCD swizzle.
// Each sb's map working set (3 views x 5ch x 256KB = 3.75 MB) fits ONE XCD's
// 4 MiB L2; default round-robin block->XCD mixes both sb sets (7.5 MB) on
// every L2 -> thrash -> gathers fall to L3/HBM latency. Remap so XCDs 0-3
// serve sb=0 rays only, XCDs 4-7 sb=1 only (bijective). Zero numeric change.
__global__ __launch_bounds__(256, 8)
void nerf_all(const float* __restrict__ rays, const float* __restrict__ poses,
              const float* __restrict__ focal, const float* __restrict__ cvec,
              const float* __restrict__ dmap, const float* __restrict__ smap,
              const float* __restrict__ nmap, const float* __restrict__ W1,
              const float* __restrict__ b1, const float* __restrict__ W2,
              const float* __restrict__ b2, const float* __restrict__ uc,
              const float* __restrict__ gn, const float* __restrict__ uf,
              float* __restrict__ out)
{
  __shared__ __align__(16) float s_pt[1024];
  __shared__ __align__(16) float s_zc[1024];
  __shared__ float s_lv[CAP];
  __shared__ int   s_li[CAP];
  __shared__ float s_lz[CAP];
  __shared__ int   s_cnt;
  __shared__ float s_cv[100];
  __shared__ int   s_ci[100];
  __shared__ float s_cz[100];
  __shared__ float s_zsel[32];
  __shared__ float s_wtot[4], s_sO[4], s_sZ[4], s_sV[4];
  __shared__ int   s_fl[4];
  __shared__ float s_zarr[N_S], s_darr[N_S];
  __shared__ float s_mlp[N_S * 4];

  const int tid = threadIdx.x;
  const int wid = tid >> 6;
  const int lane = tid & 63;
  // sb-partitioned XCD swizzle (wgid%8 == XCD on MI355X; perf heuristic only,
  // bijective on [0,4096) so correctness is mapping-independent):
  const int b = blockIdx.x;
  const int xcd = b & 7;
  const int slot = b >> 3;                 // 0..511
  const int ray = (xcd < 4) ? (xcd * 512 + slot)
                            : (2048 + (xcd - 4) * 512 + slot);
  const int sb = ray >> 11;

  // init (ordered vs later use by barrier #1)
  if (tid == 0) s_cnt = 0;
  if (tid < 100) { s_cv[tid] = 0.0f; s_ci[tid] = 0x40000000; s_cz[tid] = 0.0f; }
  if (tid < 32) s_zsel[tid] = 0.0f;

  const float* rp = rays + (size_t)ray * 8;   // uniform per block -> SGPRs
  const float ox = rp[0], oy = rp[1], oz = rp[2];
  const float dx = rp[3], dy = rp[4], dz = rp[5];
  const float nearv = rp[6], farv = rp[7];

  const float lindelta = 0.999f / 999.0f;
  const float ssv = __fdiv_rn(__fsub_rn(farv, nearv), 1000.0f);
  const float sshalf = __fmul_rn(ssv, 0.5f);

  // ---------------- Phase A0: z candidates (registers + LDS copy) ------------
  float zg0 = 0.0f, zg1 = 0.0f, zg2 = 0.0f, zg3 = 0.0f;
  {
    const float u0 = uc[(size_t)ray * N_C + tid];
    const float u1 = uc[(size_t)ray * N_C + 256 + tid];
    const float u2 = uc[(size_t)ray * N_C + 512 + tid];
    float zs;
    zs = __fadd_rn(__fmul_rn((float)tid, lindelta), __fmul_rn(u0, 0.001f));
    zg0 = __fadd_rn(__fmul_rn(nearv, __fsub_rn(1.0f, zs)), __fmul_rn(farv, zs));
    s_zc[tid] = zg0;
    zs = __fadd_rn(__fmul_rn((float)(256 + tid), lindelta), __fmul_rn(u1, 0.001f));
    zg1 = __fadd_rn(__fmul_rn(nearv, __fsub_rn(1.0f, zs)), __fmul_rn(farv, zs));
    s_zc[256 + tid] = zg1;
    zs = __fadd_rn(__fmul_rn((float)(512 + tid), lindelta), __fmul_rn(u2, 0.001f));
    zg2 = __fadd_rn(__fmul_rn(nearv, __fsub_rn(1.0f, zs)), __fmul_rn(farv, zs));
    s_zc[512 + tid] = zg2;
    if (768 + tid < N_C) {
      const float u3 = uc[(size_t)ray * N_C + 768 + tid];
      zs = __fadd_rn(__fmul_rn((float)(768 + tid), lindelta), __fmul_rn(u3, 0.001f));
      zg3 = __fadd_rn(__fmul_rn(nearv, __fsub_rn(1.0f, zs)), __fmul_rn(farv, zs));
      s_zc[768 + tid] = zg3;
    }
  }

  // ---------------- view-uniformity check (bitwise, block-uniform) -----------
  bool uni = true;
  {
    const float* p0 = poses + (size_t)(sb * N_V + 0) * 16;
    const float* p1 = poses + (size_t)(sb * N_V + 1) * 16;
    const float* p2 = poses + (size_t)(sb * N_V + 2) * 16;
#pragma unroll
    for (int i = 0; i < 12; ++i) {   // rows 0..2 of the 3x4 [R|t] are all that's used
      uni = uni && (__float_as_uint(p0[i]) == __float_as_uint(p1[i]));
      uni = uni && (__float_as_uint(p0[i]) == __float_as_uint(p2[i]));
    }
#pragma unroll
    for (int i = 0; i < 2; ++i) {
      uni = uni && (__float_as_uint(focal[(sb * N_V + 0) * 2 + i]) == __float_as_uint(focal[(sb * N_V + 1) * 2 + i]));
      uni = uni && (__float_as_uint(focal[(sb * N_V + 0) * 2 + i]) == __float_as_uint(focal[(sb * N_V + 2) * 2 + i]));
      uni = uni && (__float_as_uint(cvec[(sb * N_V + 0) * 2 + i]) == __float_as_uint(cvec[(sb * N_V + 1) * 2 + i]));
      uni = uni && (__float_as_uint(cvec[(sb * N_V + 0) * 2 + i]) == __float_as_uint(cvec[(sb * N_V + 2) * 2 + i]));
    }
  }

  // ---------------- Phase A ---------------------------------------------------
  float ptg0 = 0.0f, ptg1 = 0.0f, ptg2 = 0.0f, ptg3 = 0.0f;
  if (uni) {
    // ---- fast path: project once (v0 constants), gather all 3 views --------
    const float* pp = poses + (size_t)(sb * N_V) * 16;
    const float R00 = pp[0], R01 = pp[1], R02 = pp[2], t0 = pp[3];
    const float R10 = pp[4], R11 = pp[5], R12 = pp[6], t1 = pp[7];
    const float R20 = pp[8], R21 = pp[9], R22 = pp[10], t2 = pp[11];
    const float fx = focal[(sb * N_V) * 2 + 0];
    const float fy = focal[(sb * N_V) * 2 + 1];
    const float cx = cvec[(sb * N_V) * 2 + 0];
    const float cy = cvec[(sb * N_V) * 2 + 1];
    const float rdx = __fadd_rn(__fadd_rn(__fmul_rn(R00, dx), __fmul_rn(R01, dy)), __fmul_rn(R02, dz));
    const float rdy = __fadd_rn(__fadd_rn(__fmul_rn(R10, dx), __fmul_rn(R11, dy)), __fmul_rn(R12, dz));
    const float rdz = __fadd_rn(__fadd_rn(__fmul_rn(R20, dx), __fmul_rn(R21, dy)), __fmul_rn(R22, dz));
    const float* dm0 = dmap + (size_t)(sb * N_V + 0) * HW;
    const float* dm1 = dmap + (size_t)(sb * N_V + 1) * HW;
    const float* dm2 = dmap + (size_t)(sb * N_V + 2) * HW;
    const float* sm0 = smap + (size_t)(sb * N_V + 0) * HW;
    const float* sm1 = smap + (size_t)(sb * N_V + 1) * HW;
    const float* sm2 = smap + (size_t)(sb * N_V + 2) * HW;
    const float* nm0 = nmap + (size_t)(sb * N_V + 0) * 3 * HW;
    const float* nm1 = nmap + (size_t)(sb * N_V + 1) * 3 * HW;
    const float* nm2 = nmap + (size_t)(sb * N_V + 2) * 3 * HW;

    int lin0, lin1, lin2, lin3;
    float Zc0, Zc1, Zc2, Zc3;
    proj_one(zg0, ox, oy, oz, dx, dy, dz,
             R00, R01, R02, t0, R10, R11, R12, t1, R20, R21, R22, t2,
             fx, fy, cx, cy, lin0, Zc0);
    proj_one(zg1, ox, oy, oz, dx, dy, dz,
             R00, R01, R02, t0, R10, R11, R12, t1, R20, R21, R22, t2,
             fx, fy, cx, cy, lin1, Zc1);
    proj_one(zg2, ox, oy, oz, dx, dy, dz,
             R00, R01, R02, t0, R10, R11, R12, t1, R20, R21, R22, t2,
             fx, fy, cx, cy, lin2, Zc2);
    proj_one(zg3, ox, oy, oz, dx, dy, dz,
             R00, R01, R02, t0, R10, R11, R12, t1, R20, R21, R22, t2,
             fx, fy, cx, cy, lin3, Zc3);

    // 12 gathers issued together (deep MLP); same lin per chunk across views
    const float rd00 = dm0[lin0], rd01 = dm1[lin0], rd02 = dm2[lin0];
    const float rd10 = dm0[lin1], rd11 = dm1[lin1], rd12 = dm2[lin1];
    const float rd20 = dm0[lin2], rd21 = dm1[lin2], rd22 = dm2[lin2];
    const float rd30 = dm0[lin3], rd31 = dm1[lin3], rd32 = dm2[lin3];

    // fmax over views: values >=0 finite -> any order exact; keep v0,v1,v2
    ptg0 = gate_one(tid, lin0, Zc0, rd00, sm0, nm0, rdx, rdy, rdz, sshalf, ptg0);
    ptg0 = gate_one(tid, lin0, Zc0, rd01, sm1, nm1, rdx, rdy, rdz, sshalf, ptg0);
    ptg0 = gate_one(tid, lin0, Zc0, rd02, sm2, nm2, rdx, rdy, rdz, sshalf, ptg0);
    ptg1 = gate_one(256 + tid, lin1, Zc1, rd10, sm0, nm0, rdx, rdy, rdz, sshalf, ptg1);
    ptg1 = gate_one(256 + tid, lin1, Zc1, rd11, sm1, nm1, rdx, rdy, rdz, sshalf, ptg1);
    ptg1 = gate_one(256 + tid, lin1, Zc1, rd12, sm2, nm2, rdx, rdy, rdz, sshalf, ptg1);
    ptg2 = gate_one(512 + tid, lin2, Zc2, rd20, sm0, nm0, rdx, rdy, rdz, sshalf, ptg2);
    ptg2 = gate_one(512 + tid, lin2, Zc2, rd21, sm1, nm1, rdx, rdy, rdz, sshalf, ptg2);
    ptg2 = gate_one(512 + tid, lin2, Zc2, rd22, sm2, nm2, rdx, rdy, rdz, sshalf, ptg2);
    ptg3 = gate_one(768 + tid, lin3, Zc3, rd30, sm0, nm0, rdx, rdy, rdz, sshalf, ptg3);
    ptg3 = gate_one(768 + tid, lin3, Zc3, rd31, sm1, nm1, rdx, rdy, rdz, sshalf, ptg3);
    ptg3 = gate_one(768 + tid, lin3, Zc3, rd32, sm2, nm2, rdx, rdy, rdz, sshalf, ptg3);
  } else {
    // ---- generic fallback: per-view projection (r9 loop, exact) ------------
#pragma unroll 1
    for (int v = 0; v < N_V; ++v) {
      const float* pp = poses + (size_t)(sb * N_V + v) * 16;
      const float R00 = pp[0], R01 = pp[1], R02 = pp[2], t0 = pp[3];
      const float R10 = pp[4], R11 = pp[5], R12 = pp[6], t1 = pp[7];
      const float R20 = pp[8], R21 = pp[9], R22 = pp[10], t2 = pp[11];
      const float fx = focal[(sb * N_V + v) * 2 + 0];
      const float fy = focal[(sb * N_V + v) * 2 + 1];
      const float cx = cvec[(sb * N_V + v) * 2 + 0];
      const float cy = cvec[(sb * N_V + v) * 2 + 1];
      const float rdx = __fadd_rn(__fadd_rn(__fmul_rn(R00, dx), __fmul_rn(R01, dy)), __fmul_rn(R02, dz));
      const float rdy = __fadd_rn(__fadd_rn(__fmul_rn(R10, dx), __fmul_rn(R11, dy)), __fmul_rn(R12, dz));
      const float rdz = __fadd_rn(__fadd_rn(__fmul_rn(R20, dx), __fmul_rn(R21, dy)), __fmul_rn(R22, dz));
      const float* dmv = dmap + (size_t)(sb * N_V + v) * HW;
      const float* smv = smap + (size_t)(sb * N_V + v) * HW;
      const float* nmv = nmap + (size_t)(sb * N_V + v) * 3 * HW;

      int lin0, lin1, lin2, lin3;
      float Zc0, Zc1, Zc2, Zc3;
      proj_one(zg0, ox, oy, oz, dx, dy, dz,
               R00, R01, R02, t0, R10, R11, R12, t1, R20, R21, R22, t2,
               fx, fy, cx, cy, lin0, Zc0);
      proj_one(zg1, ox, oy, oz, dx, dy, dz,
               R00, R01, R02, t0, R10, R11, R12, t1, R20, R21, R22, t2,
               fx, fy, cx, cy, lin1, Zc1);
      proj_one(zg2, ox, oy, oz, dx, dy, dz,
               R00, R01, R02, t0, R10, R11, R12, t1, R20, R21, R22, t2,
               fx, fy, cx, cy, lin2, Zc2);
      proj_one(zg3, ox, oy, oz, dx, dy, dz,
               R00, R01, R02, t0, R10, R11, R12, t1, R20, R21, R22, t2,
               fx, fy, cx, cy, lin3, Zc3);
      const float rd0 = dmv[lin0];
      const float rd1 = dmv[lin1];
      const float rd2 = dmv[lin2];
      const float rd3 = dmv[lin3];
      ptg0 = gate_one(tid,       lin0, Zc0, rd0, smv, nmv, rdx, rdy, rdz, sshalf, ptg0);
      ptg1 = gate_one(256 + tid, lin1, Zc1, rd1, smv, nmv, rdx, rdy, rdz, sshalf, ptg1);
      ptg2 = gate_one(512 + tid, lin2, Zc2, rd2, smv, nmv, rdx, rdy, rdz, sshalf, ptg2);
      ptg3 = gate_one(768 + tid, lin3, Zc3, rd3, smv, nmv, rdx, rdy, rdz, sshalf, ptg3);
    }
  }
  s_pt[tid] = ptg0;
  s_pt[256 + tid] = ptg1;
  s_pt[512 + tid] = ptg2;
  if (768 + tid < N_C) s_pt[768 + tid] = ptg3;
  __syncthreads();                                    // #1

  // ---------------- ownership switch: thread owns 4 consecutive samples ------
  const bool act = (tid < 250);
  float ptm[4] = {0.0f, 0.0f, 0.0f, 0.0f};
  float zcr[4] = {0.0f, 0.0f, 0.0f, 0.0f};
  if (act) {
    const float4 p4 = *(const float4*)&s_pt[tid * 4];
    ptm[0] = p4.x; ptm[1] = p4.y; ptm[2] = p4.z; ptm[3] = p4.w;
    const float4 z4 = *(const float4*)&s_zc[tid * 4];
    zcr[0] = z4.x; zcr[1] = z4.y; zcr[2] = z4.z; zcr[3] = z4.w;
  }

  // ---------------- Phase B: block scan + moments ----------------------------
  float lp = 1.0f;
  if (act) {
#pragma unroll
    for (int k = 0; k < 4; ++k) lp = __fmul_rn(lp, __fsub_rn(1.0f, ptm[k]));
  }
  float inc = lp;
#pragma unroll
  for (int off = 1; off < 64; off <<= 1) {
    float o = __shfl_up(inc, off);
    if (lane >= off) inc *= o;
  }
  if (lane == 63) s_wtot[wid] = inc;
  __syncthreads();                                    // #2
  float pw = 1.0f;
  if (wid > 0) pw *= s_wtot[0];
  if (wid > 1) pw *= s_wtot[1];
  if (wid > 2) pw *= s_wtot[2];
  float exc = __shfl_up(inc, 1);
  if (lane == 0) exc = 1.0f;
  exc *= pw;

  float accO = 0.0f, accZO = 0.0f;
  bool anynz = false;
  if (act) {
    float run = exc;
#pragma unroll
    for (int k = 0; k < 4; ++k) {
      float o = ptm[k] * run;
      accO += o;
      accZO += zcr[k] * o;
      anynz |= (o != 0.0f);
      run *= (1.0f - ptm[k]);
    }
  }
  accO = wave_sum(accO);
  accZO = wave_sum(accZO);
  const int anyw = __any(anynz) ? 1 : 0;
  if (lane == 0) { s_sO[wid] = accO; s_sZ[wid] = accZO; s_fl[wid] = anyw; }
  __syncthreads();                                    // #3
  const float tO = s_sO[0] + s_sO[1] + s_sO[2] + s_sO[3];
  const float tZ = s_sZ[0] + s_sZ[1] + s_sZ[2] + s_sZ[3];
  const bool raymask = (s_fl[0] | s_fl[1] | s_fl[2] | s_fl[3]) != 0;
  const float swd = (tO > 0.0f) ? tO : 1.0f;
  const float meanz = __fdiv_rn(tZ, swd);

  float accV = 0.0f;
  if (act) {
    float run = exc;
#pragma unroll
    for (int k = 0; k < 4; ++k) {
      float o = ptm[k] * run;
      float d = zcr[k] - meanz;
      accV += o * d * d;
      run *= (1.0f - ptm[k]);
    }
  }
  accV = wave_sum(accV);
  if (lane == 0) s_sV[wid] = accV;
  __syncthreads();                                    // #4
  const float tV = s_sV[0] + s_sV[1] + s_sV[2] + s_sV[3];
  const float stdz = sqrtf(__fdiv_rn(tV, swd));

  // ---------------- Phase C0: compact nonzero candidates into LDS list -------
  {
    const bool nz0 = act && (ptm[0] > 0.0f);
    const bool nz1 = act && (ptm[1] > 0.0f);
    const bool nz2 = act && (ptm[2] > 0.0f);
    const bool nz3 = act && (ptm[3] > 0.0f);
    const int nloc = (int)nz0 + (int)nz1 + (int)nz2 + (int)nz3;
    int base = 0;
    if (nloc > 0) base = atomicAdd(&s_cnt, nloc);
    if (base + nloc <= CAP) {
      int off = base;
      if (nz0) { s_lv[off] = ptm[0]; s_li[off] = tid * 4 + 0; s_lz[off] = zcr[0]; ++off; }
      if (nz1) { s_lv[off] = ptm[1]; s_li[off] = tid * 4 + 1; s_lz[off] = zcr[1]; ++off; }
      if (nz2) { s_lv[off] = ptm[2]; s_li[off] = tid * 4 + 2; s_lz[off] = zcr[2]; ++off; }
      if (nz3) { s_lv[off] = ptm[3]; s_li[off] = tid * 4 + 3; s_lz[off] = zcr[3]; ++off; }
    }
  }
  __syncthreads();                                    // #5
  const int cnt = s_cnt;   // block-uniform

  if (cnt <= CAP) {
    // -------------- Phase C-fast: wave-0 top-25 over compacted list ----------
    if (wid == 0) {
      float rv[4]; int ri[4]; float rz[4];
#pragma unroll
      for (int j = 0; j < 4; ++j) {
        const int p = lane + j * 64;
        if (p < cnt) { rv[j] = s_lv[p]; ri[j] = s_li[p]; rz[j] = s_lz[p]; }
        else         { rv[j] = -2.0f; ri[j] = 0x40000000; rz[j] = 0.0f; }
      }
#pragma unroll 1
      for (int kk = 0; kk < 25; ++kk) {
        float bv = -2.0f; int bi = 0x40000000;
#pragma unroll
        for (int j = 0; j < 4; ++j) {
          if (rv[j] > bv || (rv[j] == bv && ri[j] < bi)) { bv = rv[j]; bi = ri[j]; }
        }
#pragma unroll
        for (int off = 1; off < 64; off <<= 1) {
          const float ov = __shfl_xor(bv, off);
          const int oi = __shfl_xor(bi, off);
          if (ov > bv || (ov == bv && oi < bi)) { bv = ov; bi = oi; }
        }
        if (bv <= 0.0f) break;   // rest of zsel stay 0 (== reference)
#pragma unroll
        for (int j = 0; j < 4; ++j) {
          if (ri[j] == bi) {      // unique global idx: exactly one lane fires
            s_zsel[kk] = rz[j];   // same-wave LDS RAW: in-order
            rv[j] = -1.0f;
          }
        }
      }
    }
  } else {
    // -------------- Phase C-fallback (exact, any data) -----------------------
    const int cbase = wid * 25;
#pragma unroll 1
    for (int kk = 0; kk < 25; ++kk) {
      float bv = -2.0f;
      int bi = 0x40000000;
      if (act) {
#pragma unroll
        for (int k = 0; k < 4; ++k) {
          if (ptm[k] > bv) { bv = ptm[k]; bi = tid * 4 + k; }
        }
      }
#pragma unroll
      for (int off = 1; off < 64; off <<= 1) {
        float ov = __shfl_xor(bv, off);
        int oi = __shfl_xor(bi, off);
        if (ov > bv || (ov == bv && oi < bi)) { bv = ov; bi = oi; }
      }
      if (bv <= 0.0f) break;
      if (tid == (bi >> 2)) {
        s_cv[cbase + kk] = bv;
        s_ci[cbase + kk] = bi;
        const int r = bi & 3;
        float zk;
        if (r == 0)      { zk = zcr[0]; ptm[0] = -1.0f; }
        else if (r == 1) { zk = zcr[1]; ptm[1] = -1.0f; }
        else if (r == 2) { zk = zcr[2]; ptm[2] = -1.0f; }
        else             { zk = zcr[3]; ptm[3] = -1.0f; }
        s_cz[cbase + kk] = zk;
      }
    }
    __syncthreads();
    if (wid == 0) {
      float c0v = s_cv[lane];
      int   c0i = s_ci[lane];
      float c0z = s_cz[lane];
      float c1v = -2.0f; int c1i = 0x40000000; float c1z = 0.0f;
      if (lane + 64 < 100) { c1v = s_cv[lane + 64]; c1i = s_ci[lane + 64]; c1z = s_cz[lane + 64]; }
#pragma unroll 1
      for (int kk = 0; kk < 25; ++kk) {
        float bv = c0v; int bi = c0i; float bz = c0z;
        if (c1v > bv || (c1v == bv && c1i < bi)) { bv = c1v; bi = c1i; bz = c1z; }
#pragma unroll
        for (int off = 1; off < 64; off <<= 1) {
          float ov = __shfl_xor(bv, off);
          int oi = __shfl_xor(bi, off);
          float oz = __shfl_xor(bz, off);
          if (ov > bv || (ov == bv && oi < bi)) { bv = ov; bi = oi; bz = oz; }
        }
        if (bv <= 0.0f) break;
        if (lane == 0) s_zsel[kk] = bz;
        if (c0i == bi) c0v = -1.0f;
        if (c1i == bi) c1v = -1.0f;
      }
    }
  }

  // ---------------- Phase D/E: gaussian slots, sort, fill, sort (wave 0) -----
  if (wid == 0) {
    float sortv;
    if (lane < N_S - N_G) {
      sortv = s_zsel[lane];
    } else if (lane < N_S) {
      const float g = gn[(size_t)ray * N_G + (lane - (N_S - N_G))];
      sortv = raymask ? (g * stdz + meanz) : 0.0f;
    } else {
      sortv = INFINITY;
    }
    float z = bitonic64(sortv, lane);
    const bool miss = (lane < N_S) && (z == 0.0f);
    const int nmiss_raw = __popcll(__ballot(miss));
    const int nmiss = (nmiss_raw < 1) ? 1 : nmiss_raw;
    const float stepf = __fdiv_rn(__fsub_rn(farv, nearv), (float)nmiss);
    if (miss) {
      const float ufv = uf[(size_t)ray * N_S + lane];
      z = __fadd_rn(__fadd_rn(nearv, __fmul_rn((float)lane, stepf)), __fmul_rn(ufv, stepf));
    }
    z = bitonic64(z, lane);
    const float zn = __shfl_down(z, 1);
    const float delta = (lane == N_S - 1) ? (farv - z) : (zn - z);
    if (lane < N_S) { s_zarr[lane] = z; s_darr[lane] = delta; }
  }
  __syncthreads();                                    // #6

  // ---------------- Phase F1: MLP, 10 samples/wave, multi-channel reduce -----
  {
    const float b2r = (lane < 4) ? b2[lane] : 0.0f;
    float w1r[24], b1r[4], w2r[16];
#pragma unroll
    for (int m = 0; m < 4; ++m) {
      const int j = lane + 64 * m;
#pragma unroll
      for (int k = 0; k < 6; ++k) w1r[k * 4 + m] = W1[k * N_HID + j];
      b1r[m] = b1[j];
      const float4 w2v = *(const float4*)(W2 + (size_t)j * 4);
      w2r[m * 4 + 0] = w2v.x; w2r[m * 4 + 1] = w2v.y;
      w2r[m * 4 + 2] = w2v.z; w2r[m * 4 + 3] = w2v.w;
    }
#pragma unroll 1
    for (int q = 0; q < 10; ++q) {
      const int s = wid * 10 + q;
      const float zq = s_zarr[s];
      const float px = ox + zq * dx;
      const float py = oy + zq * dy;
      const float pz = oz + zq * dz;
      float a0 = 0.0f, a1 = 0.0f, a2 = 0.0f, a3 = 0.0f;
#pragma unroll
      for (int m = 0; m < 4; ++m) {
        float h = b1r[m];
        h = fmaf(px, w1r[0 * 4 + m], h);
        h = fmaf(py, w1r[1 * 4 + m], h);
        h = fmaf(pz, w1r[2 * 4 + m], h);
        h = fmaf(dx, w1r[3 * 4 + m], h);
        h = fmaf(dy, w1r[4 * 4 + m], h);
        h = fmaf(dz, w1r[5 * 4 + m], h);
        h = fmaxf(h, 0.0f);
        a0 = fmaf(h, w2r[m * 4 + 0], a0);
        a1 = fmaf(h, w2r[m * 4 + 1], a1);
        a2 = fmaf(h, w2r[m * 4 + 2], a2);
        a3 = fmaf(h, w2r[m * 4 + 3], a3);
      }
      // multi-channel butterfly: lane (l&3) ends with channel (l&3) total
      const float s0 = __shfl_xor(a0, 1), s1 = __shfl_xor(a1, 1);
      const float s2 = __shfl_xor(a2, 1), s3 = __shfl_xor(a3, 1);
      const float m0 = (lane & 1) ? (a1 + s1) : (a0 + s0);
      const float m1 = (lane & 1) ? (a3 + s3) : (a2 + s2);
      const float t0 = __shfl_xor(m0, 2), t1 = __shfl_xor(m1, 2);
      float r = (lane & 2) ? (m1 + t1) : (m0 + t0);
#pragma unroll
      for (int off = 4; off < 64; off <<= 1) r += __shfl_xor(r, off);
      if (lane < 4) s_mlp[s * 4 + lane] = r + b2r;
    }
  }
  __syncthreads();                                    // #7

  // ---------------- Phase F2: composite + output (wave 0) --------------------
  if (wid == 0) {
    float alpha = 0.0f, r0 = 0.0f, r1 = 0.0f, r2 = 0.0f, zl = 0.0f;
    float factor = 1.0f;
    if (lane < N_S) {
      zl = s_zarr[lane];
      const float dl = s_darr[lane];
      r0 = s_mlp[lane * 4 + 0];
      r1 = s_mlp[lane * 4 + 1];
      r2 = s_mlp[lane * 4 + 2];
      const float rsig = fmaxf(s_mlp[lane * 4 + 3], 0.0f);
      alpha = 1.0f - expf(-dl * rsig);
      factor = (1.0f - alpha) + 1e-10f;
    }
    float incp = factor;
#pragma unroll
    for (int off = 1; off < 64; off <<= 1) {
      float o = __shfl_up(incp, off);
      if (lane >= off) incp *= o;
    }
    float T = __shfl_up(incp, 1);
    if (lane == 0) T = 1.0f;

    const float w = (lane < N_S) ? alpha * T : 0.0f;
    const float wz = (lane < N_S) ? w * zl : 0.0f;
    const float wr0 = (lane < N_S) ? w * r0 : 0.0f;
    const float wr1 = (lane < N_S) ? w * r1 : 0.0f;
    const float wr2 = (lane < N_S) ? w * r2 : 0.0f;

    const float wsum = wave_sum(w);
    const float dsum = wave_sum(wz);
    const float c0s = wave_sum(wr0);
    const float c1s = wave_sum(wr1);
    const float c2s = wave_sum(wr2);

    if (lane < N_S) out[(size_t)ray * N_S + lane] = w;
    if (lane == 0) {
      float* rgbo = out + (size_t)N_SB * N_R * N_S + (size_t)ray * 3;
      rgbo[0] = (c0s + 1.0f) - wsum;
      rgbo[1] = (c1s + 1.0f) - wsum;
      rgbo[2] = (c2s + 1.0f) - wsum;
      out[(size_t)N_SB * N_R * N_S + (size_t)N_SB * N_R * 3 + ray] = dsum;
    }
  }
}

extern "C" void kernel_launch(void* const* d_in, const int* in_sizes, int n_in,
                              void* d_out, int out_size, void* d_ws, size_t ws_size,
                              hipStream_t stream) {
  const float* rays  = (const float*)d_in[0];
  const float* poses = (const float*)d_in[1];
  const float* focal = (const float*)d_in[2];
  const float* cvec  = (const float*)d_in[3];
  const float* dmap  = (const float*)d_in[4];
  const float* smap  = (const float*)d_in[5];
  const float* nmap  = (const float*)d_in[6];
  const float* W1p   = (const float*)d_in[7];
  const float* b1p   = (const float*)d_in[8];
  const float* W2p   = (const float*)d_in[9];
  const float* b2p   = (const float*)d_in[10];
  const float* ucp   = (const float*)d_in[11];
  const float* gnp   = (const float*)d_in[12];
  const float* ufp   = (const float*)d_in[13];
  float* outp = (float*)d_out;

  dim3 grid(N_SB * N_R);   // one ray per block (index swizzled in-kernel)
  dim3 block(256);
  nerf_all<<<grid, block, 0, stream>>>(rays, poses, focal, cvec, dmap, smap, nmap,
                                       W1p, b1p, W2p, b2p, ucp, gnp, ufp, outp);
}